// Round 1
// baseline (1397.657 us; speedup 1.0000x reference)
//
#include <hip/hip_runtime.h>
#include <stdint.h>
#include <math.h>

// Problem constants
#define MM 256          // B*S = 32*8
#define KD 1024         // D
#define VV 50257        // vocab

// RNG variant switches (flip if ONLY tokens output mismatches)
#define RNG_PARTITIONABLE 1   // jax_threefry_partitionable (default True in modern JAX)
#define RNG_XOR_FOLD 1        // 32-bit bits = out1 ^ out2 (partitionable path)

static constexpr size_t OUT_LOGITS = 0;
static constexpr size_t OUT_TOKENS = (size_t)MM * VV;            // 12865792
static constexpr size_t OUT_PROBS  = OUT_TOKENS + MM;            // 12866048
static constexpr size_t OUT_LOGPR  = OUT_PROBS + (size_t)MM * VV;// 25731840

// ---------------- Threefry-2x32-20 (JAX-compatible) ----------------
__device__ __forceinline__ unsigned rotl32(unsigned x, int r) {
  return (x << r) | (x >> (32 - r));
}

__device__ __forceinline__ uint2 threefry2x32(unsigned k0, unsigned k1,
                                              unsigned x0, unsigned x1) {
  unsigned ks[3] = {k0, k1, k0 ^ k1 ^ 0x1BD11BDAu};
  const int rot[8] = {13, 15, 26, 6, 17, 29, 16, 24};
  x0 += ks[0]; x1 += ks[1];
  #pragma unroll
  for (int g = 0; g < 5; ++g) {
    const int base = (g & 1) ? 4 : 0;
    #pragma unroll
    for (int i = 0; i < 4; ++i) {
      x0 += x1;
      x1 = rotl32(x1, rot[base + i]);
      x1 ^= x0;
    }
    x0 += ks[(g + 1) % 3];
    x1 += ks[(g + 2) % 3] + (unsigned)(g + 1);
  }
  return make_uint2(x0, x1);
}

__device__ __forceinline__ float gumbel_at(unsigned flat) {
  unsigned w;
#if RNG_PARTITIONABLE
  uint2 r = threefry2x32(0u, 42u, 0u, flat);   // hi32(i)=0 for i < 2^32
#if RNG_XOR_FOLD
  w = r.x ^ r.y;
#else
  w = r.x;
#endif
#else
  const unsigned half = (unsigned)((size_t)MM * VV / 2);   // 6432896
  unsigned x0, x1; bool first;
  if (flat < half) { x0 = flat; x1 = flat + half; first = true; }
  else             { x0 = flat - half; x1 = flat; first = false; }
  uint2 r = threefry2x32(0u, 42u, x0, x1);
  w = first ? r.x : r.y;
#endif
  // JAX uniform in [tiny, 1): bits>>9 | 1.0f, -1, then *1 + tiny, max(tiny,.)
  unsigned fb = (w >> 9) | 0x3F800000u;
  float f = __uint_as_float(fb) - 1.0f;
  const float tiny = 1.1754943508222875e-38f;
  float u = fmaxf(tiny, f + tiny);
  // gumbel = -log(-log(u)); use double-backed log for correctly-rounded f32
  float t1 = (float)log((double)u);
  float t3 = (float)log((double)(-t1));
  return -t3;
}

// ---------------- K1: f32 GEMM  logits = psi_r Wr^T + psi_i Wi^T + bias ----
#define BN 64
#define BK 32
#define GEMM_THREADS 512

__global__ __launch_bounds__(GEMM_THREADS)
void k_gemm(const float* __restrict__ psi_r, const float* __restrict__ psi_i,
            const float* __restrict__ Wr, const float* __restrict__ Wi,
            const float* __restrict__ bias, float* __restrict__ logits) {
  __shared__ __align__(16) float psiT[BK][MM];     // 32 KB, [k][m]
  __shared__ __align__(16) float w_s[BN][BK + 1];  // 8.25 KB, [n][k] padded

  const int tid = threadIdx.x;
  const int nb  = blockIdx.x * BN;
  const int tm  = tid >> 4;   // 0..31 -> rows tm*8 .. tm*8+7
  const int tn  = tid & 15;   // 0..15 -> cols tn*4 .. tn*4+3

  float acc[8][4];
  #pragma unroll
  for (int i = 0; i < 8; ++i)
    #pragma unroll
    for (int j = 0; j < 4; ++j) acc[i][j] = 0.f;

  for (int src = 0; src < 2; ++src) {
    const float* __restrict__ psi = src ? psi_i : psi_r;
    const float* __restrict__ W   = src ? Wi : Wr;
    for (int kk = 0; kk < KD; kk += BK) {
      __syncthreads();
      // stage psi tile transposed: 256 rows x 32 k
      #pragma unroll
      for (int it = 0; it < 4; ++it) {
        int q  = tid + it * GEMM_THREADS;  // 0..2047
        int m  = q >> 3;
        int k4 = q & 7;
        float4 v = *reinterpret_cast<const float4*>(&psi[m * KD + kk + k4 * 4]);
        psiT[k4 * 4 + 0][m] = v.x;
        psiT[k4 * 4 + 1][m] = v.y;
        psiT[k4 * 4 + 2][m] = v.z;
        psiT[k4 * 4 + 3][m] = v.w;
      }
      // stage W tile: 64 n-rows x 32 k
      {
        int n  = tid >> 3;
        int k4 = tid & 7;
        int gn = nb + n;
        float4 v = make_float4(0.f, 0.f, 0.f, 0.f);
        if (gn < VV)
          v = *reinterpret_cast<const float4*>(&W[(size_t)gn * KD + kk + k4 * 4]);
        w_s[n][k4 * 4 + 0] = v.x;
        w_s[n][k4 * 4 + 1] = v.y;
        w_s[n][k4 * 4 + 2] = v.z;
        w_s[n][k4 * 4 + 3] = v.w;
      }
      __syncthreads();
      #pragma unroll 8
      for (int k = 0; k < BK; ++k) {
        float4 a0 = *reinterpret_cast<const float4*>(&psiT[k][tm * 8]);
        float4 a1 = *reinterpret_cast<const float4*>(&psiT[k][tm * 8 + 4]);
        float w0 = w_s[tn * 4 + 0][k];
        float w1 = w_s[tn * 4 + 1][k];
        float w2 = w_s[tn * 4 + 2][k];
        float w3 = w_s[tn * 4 + 3][k];
        float a[8] = {a0.x, a0.y, a0.z, a0.w, a1.x, a1.y, a1.z, a1.w};
        #pragma unroll
        for (int i = 0; i < 8; ++i) {
          acc[i][0] += a[i] * w0;
          acc[i][1] += a[i] * w1;
          acc[i][2] += a[i] * w2;
          acc[i][3] += a[i] * w3;
        }
      }
    }
  }
  #pragma unroll
  for (int j = 0; j < 4; ++j) {
    int n = nb + tn * 4 + j;
    if (n < VV) {
      float b = bias[n];
      #pragma unroll
      for (int i = 0; i < 8; ++i) {
        int m = tm * 8 + i;
        logits[(size_t)m * VV + n] = acc[i][j] + b;
      }
    }
  }
}

// ---------------- K2: per-row max & log-sum-exp --------------------------
__global__ __launch_bounds__(256)
void k_rowstats(const float* __restrict__ logits, float* __restrict__ ws) {
  const int row = blockIdx.x;
  const float* __restrict__ x = logits + (size_t)row * VV;
  float lm = -INFINITY, ls = 0.f;
  for (int i = threadIdx.x; i < VV; i += 256) {
    float v = x[i];
    if (v <= lm) {
      ls += expf(v - lm);
    } else {
      ls = ls * expf(lm - v) + 1.f;
      lm = v;
    }
  }
  __shared__ float sm[256], ss[256];
  sm[threadIdx.x] = lm;
  ss[threadIdx.x] = ls;
  __syncthreads();
  for (int off = 128; off > 0; off >>= 1) {
    if (threadIdx.x < off) {
      float m1 = sm[threadIdx.x], s1 = ss[threadIdx.x];
      float m2 = sm[threadIdx.x + off], s2 = ss[threadIdx.x + off];
      float m = fmaxf(m1, m2);
      ss[threadIdx.x] = s1 * expf(m1 - m) + s2 * expf(m2 - m);
      sm[threadIdx.x] = m;
    }
    __syncthreads();
  }
  if (threadIdx.x == 0) {
    ws[row * 2 + 0] = sm[0];
    ws[row * 2 + 1] = logf(ss[0]);
  }
}

// ---------------- K3: log_probs + zero probs chunk -----------------------
__global__ __launch_bounds__(256)
void k_logprobs(const float* __restrict__ logits, const float* __restrict__ ws,
                float* __restrict__ logpr, float* __restrict__ probs) {
  const int total4 = (MM * VV) / 4;  // 3216448
  for (int q = blockIdx.x * blockDim.x + threadIdx.x; q < total4;
       q += gridDim.x * blockDim.x) {
    int idx = q * 4;
    float4 v = *reinterpret_cast<const float4*>(&logits[idx]);
    float in[4] = {v.x, v.y, v.z, v.w};
    float o[4];
    #pragma unroll
    for (int j = 0; j < 4; ++j) {
      unsigned row = (unsigned)(idx + j) / (unsigned)VV;
      o[j] = (in[j] - ws[row * 2 + 0]) - ws[row * 2 + 1];
    }
    *reinterpret_cast<float4*>(&logpr[idx]) = make_float4(o[0], o[1], o[2], o[3]);
    *reinterpret_cast<float4*>(&probs[idx]) = make_float4(0.f, 0.f, 0.f, 0.f);
  }
}

// ---------------- K4: top-k/top-p filter, probs scatter, token sample ----
#define CAP 1024

__device__ __forceinline__ unsigned ordf(float f) {
  unsigned u = __float_as_uint(f);
  return u ^ ((u >> 31) ? 0xFFFFFFFFu : 0x80000000u);
}

__global__ __launch_bounds__(256)
void k_sample(const float* __restrict__ logits, float* __restrict__ probs,
              float* __restrict__ tokens) {
  const int row = blockIdx.x;
  const int tid = threadIdx.x;
  const float* __restrict__ x = logits + (size_t)row * VV;

  __shared__ unsigned hist[4096];
  __shared__ float cv[CAP];
  __shared__ int   ci[CAP];
  __shared__ unsigned s_cnt;
  __shared__ unsigned s_lo;
  __shared__ float top_v[50];
  __shared__ int   top_i[50];
  __shared__ float s_sp[50];
  __shared__ float red_v[256];
  __shared__ int   red_i[256];
  __shared__ int   red_s[256];

  for (int i = tid; i < 4096; i += 256) hist[i] = 0u;
  __syncthreads();

  for (int i = tid; i < VV; i += 256)
    atomicAdd(&hist[ordf(x[i]) >> 20], 1u);
  __syncthreads();

  if (tid == 0) {
    unsigned cum = 0;
    int bin = 0;
    for (int b = 4095; b >= 0; --b) {
      cum += hist[b];
      if (cum >= 50u) { bin = b; break; }
    }
    s_lo = (unsigned)bin << 20;
    s_cnt = 0u;
  }
  __syncthreads();

  const unsigned lo = s_lo;
  for (int i = tid; i < VV; i += 256) {
    float v = x[i];
    if (ordf(v) >= lo) {
      unsigned pos = atomicAdd(&s_cnt, 1u);
      if (pos < CAP) { cv[pos] = v; ci[pos] = i; }
    }
  }
  __syncthreads();
  const int ncand = (int)min(s_cnt, (unsigned)CAP);

  // 50 rounds of argmax (value desc, index asc)
  for (int it = 0; it < 50; ++it) {
    float bv = -INFINITY;
    int bi = 0x7FFFFFFF, bs = 0;
    for (int c = tid; c < ncand; c += 256) {
      float v = cv[c];
      int id = ci[c];
      if (v > bv || (v == bv && id < bi)) { bv = v; bi = id; bs = c; }
    }
    red_v[tid] = bv; red_i[tid] = bi; red_s[tid] = bs;
    __syncthreads();
    for (int off = 128; off > 0; off >>= 1) {
      if (tid < off) {
        float v2 = red_v[tid + off];
        int i2 = red_i[tid + off];
        if (v2 > red_v[tid] || (v2 == red_v[tid] && i2 < red_i[tid])) {
          red_v[tid] = v2; red_i[tid] = i2; red_s[tid] = red_s[tid + off];
        }
      }
      __syncthreads();
    }
    if (tid == 0) {
      top_v[it] = red_v[0];
      top_i[it] = red_i[0];
      cv[red_s[0]] = -INFINITY;   // mark used
    }
    __syncthreads();
  }

  if (tid == 0) {
    // softmax over top-50 (matches ref: only survivors are finite)
    float mx = top_v[0];
    float Z = 0.f;
    for (int i = 0; i < 50; ++i) { s_sp[i] = expf(top_v[i] - mx); Z += s_sp[i]; }
    // top-p: keep while exclusive prefix (of sp/Z) < 0.95, always keep first
    float cum = 0.f, Z2 = 0.f;
    int nkeep = 0;
    for (int i = 0; i < 50; ++i) {
      bool keep = (i == 0) || (cum < 0.95f);
      if (!keep) break;
      nkeep = i + 1;
      Z2 += s_sp[i];
      cum += s_sp[i] / Z;
    }
    // probs scatter + gumbel-argmax token
    float bestval = -INFINITY;
    int besttok = 0x7FFFFFFF;
    for (int i = 0; i < nkeep; ++i) {
      int idx = top_i[i];
      probs[(size_t)row * VV + idx] = s_sp[i] / Z2;
      unsigned flat = (unsigned)(row * VV + idx);
      float t = top_v[i] + gumbel_at(flat);
      if (t > bestval || (t == bestval && idx < besttok)) {
        bestval = t; besttok = idx;
      }
    }
    tokens[row] = (float)besttok;
  }
}

// ---------------- launch --------------------------------------------------
extern "C" void kernel_launch(void* const* d_in, const int* in_sizes, int n_in,
                              void* d_out, int out_size, void* d_ws, size_t ws_size,
                              hipStream_t stream) {
  const float* psi_r = (const float*)d_in[0];
  const float* psi_i = (const float*)d_in[1];
  const float* Wr    = (const float*)d_in[2];
  const float* Wi    = (const float*)d_in[3];
  const float* bias  = (const float*)d_in[4];
  float* out = (float*)d_out;
  float* ws  = (float*)d_ws;

  float* logits = out + OUT_LOGITS;
  float* tokens = out + OUT_TOKENS;
  float* probs  = out + OUT_PROBS;
  float* logpr  = out + OUT_LOGPR;

  const int nblk = (VV + BN - 1) / BN;  // 786
  k_gemm<<<nblk, GEMM_THREADS, 0, stream>>>(psi_r, psi_i, Wr, Wi, bias, logits);
  k_rowstats<<<MM, 256, 0, stream>>>(logits, ws);
  k_logprobs<<<2048, 256, 0, stream>>>(logits, ws, logpr, probs);
  k_sample<<<MM, 256, 0, stream>>>(logits, probs, tokens);
}

// Round 2
// 712.438 us; speedup vs baseline: 1.9618x; 1.9618x over previous
//
#include <hip/hip_runtime.h>
#include <stdint.h>
#include <math.h>

// Problem constants
#define MM 256          // B*S = 32*8
#define KD 1024         // D
#define K2 2048         // combined K (real|imag)
#define VV 50257        // vocab

static constexpr size_t OUT_LOGITS = 0;
static constexpr size_t OUT_TOKENS = (size_t)MM * VV;            // 12865792
static constexpr size_t OUT_PROBS  = OUT_TOKENS + MM;            // 12866048
static constexpr size_t OUT_LOGPR  = OUT_PROBS + (size_t)MM * VV;// 25731840

typedef __attribute__((ext_vector_type(8))) short bf16x8;
typedef __attribute__((ext_vector_type(4))) float f32x4;

// ---------------- bf16 split helpers --------------------------------------
__device__ __forceinline__ ushort f2bf(float x) {
  unsigned u = __float_as_uint(x);
  unsigned r = u + 0x7FFFu + ((u >> 16) & 1u);   // RNE
  return (ushort)(r >> 16);
}
__device__ __forceinline__ float bf2f(ushort h) {
  return __uint_as_float(((unsigned)h) << 16);
}

// ---------------- Threefry-2x32-20 (JAX-compatible) ----------------
#define RNG_PARTITIONABLE 1
#define RNG_XOR_FOLD 1

__device__ __forceinline__ unsigned rotl32(unsigned x, int r) {
  return (x << r) | (x >> (32 - r));
}

__device__ __forceinline__ uint2 threefry2x32(unsigned k0, unsigned k1,
                                              unsigned x0, unsigned x1) {
  unsigned ks[3] = {k0, k1, k0 ^ k1 ^ 0x1BD11BDAu};
  const int rot[8] = {13, 15, 26, 6, 17, 29, 16, 24};
  x0 += ks[0]; x1 += ks[1];
  #pragma unroll
  for (int g = 0; g < 5; ++g) {
    const int base = (g & 1) ? 4 : 0;
    #pragma unroll
    for (int i = 0; i < 4; ++i) {
      x0 += x1;
      x1 = rotl32(x1, rot[base + i]);
      x1 ^= x0;
    }
    x0 += ks[(g + 1) % 3];
    x1 += ks[(g + 2) % 3] + (unsigned)(g + 1);
  }
  return make_uint2(x0, x1);
}

__device__ __forceinline__ float gumbel_at(unsigned flat) {
  unsigned w;
#if RNG_PARTITIONABLE
  uint2 r = threefry2x32(0u, 42u, 0u, flat);
#if RNG_XOR_FOLD
  w = r.x ^ r.y;
#else
  w = r.x;
#endif
#else
  const unsigned half = (unsigned)((size_t)MM * VV / 2);
  unsigned x0, x1; bool first;
  if (flat < half) { x0 = flat; x1 = flat + half; first = true; }
  else             { x0 = flat - half; x1 = flat; first = false; }
  uint2 r = threefry2x32(0u, 42u, x0, x1);
  w = first ? r.x : r.y;
#endif
  unsigned fb = (w >> 9) | 0x3F800000u;
  float f = __uint_as_float(fb) - 1.0f;
  const float tiny = 1.1754943508222875e-38f;
  float u = fmaxf(tiny, f + tiny);
  float t1 = (float)log((double)u);
  float t3 = (float)log((double)(-t1));
  return -t3;
}

// ---------------- K1: split-bf16 MFMA GEMM --------------------------------
// logits[m][v] = sum_k psiC[m][k'] * WC[v][k'] + bias[v],  k' over 2048
// f32 operands split into (hi, lo) bf16; 3 MFMA products (drop lo*lo).
#define BM 256
#define BN 64
#define BK 64
#define GT 512

__global__ __launch_bounds__(GT, 4)
void k_gemm(const float* __restrict__ psi_r, const float* __restrict__ psi_i,
            const float* __restrict__ Wr, const float* __restrict__ Wi,
            const float* __restrict__ bias, float* __restrict__ logits) {
  __shared__ ushort sAh[BM * BK];   // 32 KB
  __shared__ ushort sAl[BM * BK];   // 32 KB
  __shared__ ushort sBh[BN * BK];   // 8 KB
  __shared__ ushort sBl[BN * BK];   // 8 KB

  const int tid  = threadIdx.x;
  const int lane = tid & 63;
  const int wid  = tid >> 6;    // 0..7
  const int wm   = wid >> 1;    // 0..3  -> m block of 64
  const int wn   = wid & 1;     // 0..1  -> n block of 32
  const int vb   = blockIdx.x * BN;

  const int lr = lane & 15;     // fragment row/col
  const int lg = lane >> 4;     // k-group

  f32x4 acc[4][2];
  #pragma unroll
  for (int i = 0; i < 4; ++i)
    #pragma unroll
    for (int j = 0; j < 2; ++j)
      #pragma unroll
      for (int q = 0; q < 4; ++q) acc[i][j][q] = 0.f;

  for (int kk = 0; kk < K2; kk += BK) {
    const float* __restrict__ Asrc = (kk < KD) ? psi_r : psi_i;
    const float* __restrict__ Bsrc = (kk < KD) ? Wr : Wi;
    const int ko = kk & (KD - 1);

    __syncthreads();

    // stage A: 256 x 64 f32 -> hi/lo bf16, swizzled
    #pragma unroll
    for (int it = 0; it < 8; ++it) {
      int q  = tid + it * GT;          // 0..4095
      int m  = q >> 4;
      int c4 = (q & 15) << 2;          // f32 col, step 4
      float4 v = *reinterpret_cast<const float4*>(&Asrc[m * KD + ko + c4]);
      ushort h0 = f2bf(v.x), h1 = f2bf(v.y), h2 = f2bf(v.z), h3 = f2bf(v.w);
      ushort l0 = f2bf(v.x - bf2f(h0)), l1 = f2bf(v.y - bf2f(h1));
      ushort l2 = f2bf(v.z - bf2f(h2)), l3 = f2bf(v.w - bf2f(h3));
      int eoff = (m * BK + c4) ^ ((m & 7) << 3);
      uint2 ph = make_uint2((unsigned)h0 | ((unsigned)h1 << 16),
                            (unsigned)h2 | ((unsigned)h3 << 16));
      uint2 pl = make_uint2((unsigned)l0 | ((unsigned)l1 << 16),
                            (unsigned)l2 | ((unsigned)l3 << 16));
      *reinterpret_cast<uint2*>(&sAh[eoff]) = ph;
      *reinterpret_cast<uint2*>(&sAl[eoff]) = pl;
    }
    // stage B: 64 x 64 f32 -> hi/lo bf16, swizzled
    #pragma unroll
    for (int it = 0; it < 2; ++it) {
      int q  = tid + it * GT;          // 0..1023
      int r  = q >> 4;
      int c4 = (q & 15) << 2;
      int gn = vb + r;
      float4 v = make_float4(0.f, 0.f, 0.f, 0.f);
      if (gn < VV)
        v = *reinterpret_cast<const float4*>(&Bsrc[(size_t)gn * KD + ko + c4]);
      ushort h0 = f2bf(v.x), h1 = f2bf(v.y), h2 = f2bf(v.z), h3 = f2bf(v.w);
      ushort l0 = f2bf(v.x - bf2f(h0)), l1 = f2bf(v.y - bf2f(h1));
      ushort l2 = f2bf(v.z - bf2f(h2)), l3 = f2bf(v.w - bf2f(h3));
      int eoff = (r * BK + c4) ^ ((r & 7) << 3);
      uint2 ph = make_uint2((unsigned)h0 | ((unsigned)h1 << 16),
                            (unsigned)h2 | ((unsigned)h3 << 16));
      uint2 pl = make_uint2((unsigned)l0 | ((unsigned)l1 << 16),
                            (unsigned)l2 | ((unsigned)l3 << 16));
      *reinterpret_cast<uint2*>(&sBh[eoff]) = ph;
      *reinterpret_cast<uint2*>(&sBl[eoff]) = pl;
    }
    __syncthreads();

    // compute: 2 k-steps of 32, 4 m-frags x 2 n-frags x 3 products
    #pragma unroll
    for (int k0 = 0; k0 < BK; k0 += 32) {
      const int kbase = k0 + lg * 8;
      bf16x8 bh[2], bl[2];
      #pragma unroll
      for (int ni = 0; ni < 2; ++ni) {
        int r = wn * 32 + ni * 16 + lr;
        int eoff = (r * BK + kbase) ^ ((r & 7) << 3);
        bh[ni] = *reinterpret_cast<const bf16x8*>(&sBh[eoff]);
        bl[ni] = *reinterpret_cast<const bf16x8*>(&sBl[eoff]);
      }
      #pragma unroll
      for (int mi = 0; mi < 4; ++mi) {
        int m = wm * 64 + mi * 16 + lr;
        int eoff = (m * BK + kbase) ^ ((m & 7) << 3);
        bf16x8 ah = *reinterpret_cast<const bf16x8*>(&sAh[eoff]);
        bf16x8 al = *reinterpret_cast<const bf16x8*>(&sAl[eoff]);
        #pragma unroll
        for (int ni = 0; ni < 2; ++ni) {
          acc[mi][ni] = __builtin_amdgcn_mfma_f32_16x16x32_bf16(ah, bh[ni], acc[mi][ni], 0, 0, 0);
          acc[mi][ni] = __builtin_amdgcn_mfma_f32_16x16x32_bf16(al, bh[ni], acc[mi][ni], 0, 0, 0);
          acc[mi][ni] = __builtin_amdgcn_mfma_f32_16x16x32_bf16(ah, bl[ni], acc[mi][ni], 0, 0, 0);
        }
      }
    }
  }

  // epilogue: D layout col=lane&15, row=(lane>>4)*4+reg
  #pragma unroll
  for (int ni = 0; ni < 2; ++ni) {
    int v = vb + wn * 32 + ni * 16 + lr;
    if (v < VV) {
      float b = bias[v];
      #pragma unroll
      for (int mi = 0; mi < 4; ++mi) {
        #pragma unroll
        for (int j = 0; j < 4; ++j) {
          int m = wm * 64 + mi * 16 + lg * 4 + j;
          logits[(size_t)m * VV + v] = acc[mi][ni][j] + b;
        }
      }
    }
  }
}

// ---------------- K2: per-row max & log-sum-exp --------------------------
__global__ __launch_bounds__(512)
void k_rowstats(const float* __restrict__ logits, float* __restrict__ ws) {
  const int row = blockIdx.x;
  const float* __restrict__ x = logits + (size_t)row * VV;
  float lm = -INFINITY, ls = 0.f;
  for (int i = threadIdx.x; i < VV; i += 512) {
    float v = x[i];
    if (v <= lm) {
      ls += expf(v - lm);
    } else {
      ls = ls * expf(lm - v) + 1.f;
      lm = v;
    }
  }
  __shared__ float sm[512], ss[512];
  sm[threadIdx.x] = lm;
  ss[threadIdx.x] = ls;
  __syncthreads();
  for (int off = 256; off > 0; off >>= 1) {
    if (threadIdx.x < off) {
      float m1 = sm[threadIdx.x], s1 = ss[threadIdx.x];
      float m2 = sm[threadIdx.x + off], s2 = ss[threadIdx.x + off];
      float m = fmaxf(m1, m2);
      ss[threadIdx.x] = s1 * expf(m1 - m) + s2 * expf(m2 - m);
      sm[threadIdx.x] = m;
    }
    __syncthreads();
  }
  if (threadIdx.x == 0) {
    ws[row * 2 + 0] = sm[0];
    ws[row * 2 + 1] = logf(ss[0]);
  }
}

// ---------------- K3: log_probs + zero probs chunk -----------------------
__global__ __launch_bounds__(256)
void k_logprobs(const float* __restrict__ logits, const float* __restrict__ ws,
                float* __restrict__ logpr, float* __restrict__ probs) {
  const int total4 = (MM * VV) / 4;  // 3216448
  for (int q = blockIdx.x * blockDim.x + threadIdx.x; q < total4;
       q += gridDim.x * blockDim.x) {
    int idx = q * 4;
    float4 v = *reinterpret_cast<const float4*>(&logits[idx]);
    float in[4] = {v.x, v.y, v.z, v.w};
    float o[4];
    #pragma unroll
    for (int j = 0; j < 4; ++j) {
      unsigned row = (unsigned)(idx + j) / (unsigned)VV;
      o[j] = (in[j] - ws[row * 2 + 0]) - ws[row * 2 + 1];
    }
    *reinterpret_cast<float4*>(&logpr[idx]) = make_float4(o[0], o[1], o[2], o[3]);
    *reinterpret_cast<float4*>(&probs[idx]) = make_float4(0.f, 0.f, 0.f, 0.f);
  }
}

// ---------------- K4: top-k/top-p filter, probs scatter, token sample ----
#define CAP 1024
#define ST 512

__device__ __forceinline__ unsigned ordf(float f) {
  unsigned u = __float_as_uint(f);
  return u ^ ((u >> 31) ? 0xFFFFFFFFu : 0x80000000u);
}

__global__ __launch_bounds__(ST)
void k_sample(const float* __restrict__ logits, float* __restrict__ probs,
              float* __restrict__ tokens) {
  const int row = blockIdx.x;
  const int tid = threadIdx.x;
  const float* __restrict__ x = logits + (size_t)row * VV;

  __shared__ unsigned hist[4096];
  __shared__ float cv[CAP];
  __shared__ int   ci[CAP];
  __shared__ unsigned s_cnt;
  __shared__ unsigned s_lo;
  __shared__ float top_v[50];
  __shared__ int   top_i[50];
  __shared__ float s_sp[50];
  __shared__ float red_v[ST];
  __shared__ int   red_i[ST];
  __shared__ int   red_s[ST];

  for (int i = tid; i < 4096; i += ST) hist[i] = 0u;
  __syncthreads();

  for (int i = tid; i < VV; i += ST)
    atomicAdd(&hist[ordf(x[i]) >> 20], 1u);
  __syncthreads();

  if (tid == 0) {
    unsigned cum = 0;
    int bin = 0;
    for (int b = 4095; b >= 0; --b) {
      cum += hist[b];
      if (cum >= 50u) { bin = b; break; }
    }
    s_lo = (unsigned)bin << 20;
    s_cnt = 0u;
  }
  __syncthreads();

  const unsigned lo = s_lo;
  for (int i = tid; i < VV; i += ST) {
    float v = x[i];
    if (ordf(v) >= lo) {
      unsigned pos = atomicAdd(&s_cnt, 1u);
      if (pos < CAP) { cv[pos] = v; ci[pos] = i; }
    }
  }
  __syncthreads();
  const int ncand = (int)min(s_cnt, (unsigned)CAP);

  // 50 rounds of argmax (value desc, index asc)
  for (int it = 0; it < 50; ++it) {
    float bv = -INFINITY;
    int bi = 0x7FFFFFFF, bs = 0;
    for (int c = tid; c < ncand; c += ST) {
      float v = cv[c];
      int id = ci[c];
      if (v > bv || (v == bv && id < bi)) { bv = v; bi = id; bs = c; }
    }
    red_v[tid] = bv; red_i[tid] = bi; red_s[tid] = bs;
    __syncthreads();
    for (int off = ST / 2; off > 0; off >>= 1) {
      if (tid < off) {
        float v2 = red_v[tid + off];
        int i2 = red_i[tid + off];
        if (v2 > red_v[tid] || (v2 == red_v[tid] && i2 < red_i[tid])) {
          red_v[tid] = v2; red_i[tid] = i2; red_s[tid] = red_s[tid + off];
        }
      }
      __syncthreads();
    }
    if (tid == 0) {
      top_v[it] = red_v[0];
      top_i[it] = red_i[0];
      cv[red_s[0]] = -INFINITY;   // mark used
    }
    __syncthreads();
  }

  if (tid == 0) {
    float mx = top_v[0];
    float Z = 0.f;
    for (int i = 0; i < 50; ++i) { s_sp[i] = expf(top_v[i] - mx); Z += s_sp[i]; }
    float cum = 0.f, Z2 = 0.f;
    int nkeep = 0;
    for (int i = 0; i < 50; ++i) {
      bool keep = (i == 0) || (cum < 0.95f);
      if (!keep) break;
      nkeep = i + 1;
      Z2 += s_sp[i];
      cum += s_sp[i] / Z;
    }
    float bestval = -INFINITY;
    int besttok = 0x7FFFFFFF;
    for (int i = 0; i < nkeep; ++i) {
      int idx = top_i[i];
      probs[(size_t)row * VV + idx] = s_sp[i] / Z2;
      unsigned flat = (unsigned)(row * VV + idx);
      float t = top_v[i] + gumbel_at(flat);
      if (t > bestval || (t == bestval && idx < besttok)) {
        bestval = t; besttok = idx;
      }
    }
    tokens[row] = (float)besttok;
  }
}

// ---------------- launch --------------------------------------------------
extern "C" void kernel_launch(void* const* d_in, const int* in_sizes, int n_in,
                              void* d_out, int out_size, void* d_ws, size_t ws_size,
                              hipStream_t stream) {
  const float* psi_r = (const float*)d_in[0];
  const float* psi_i = (const float*)d_in[1];
  const float* Wr    = (const float*)d_in[2];
  const float* Wi    = (const float*)d_in[3];
  const float* bias  = (const float*)d_in[4];
  float* out = (float*)d_out;
  float* ws  = (float*)d_ws;

  float* logits = out + OUT_LOGITS;
  float* tokens = out + OUT_TOKENS;
  float* probs  = out + OUT_PROBS;
  float* logpr  = out + OUT_LOGPR;

  const int nblk = (VV + BN - 1) / BN;  // 786
  k_gemm<<<nblk, GT, 0, stream>>>(psi_r, psi_i, Wr, Wi, bias, logits);
  k_rowstats<<<MM, 512, 0, stream>>>(logits, ws);
  k_logprobs<<<3072, 256, 0, stream>>>(logits, ws, logpr, probs);
  k_sample<<<MM, ST, 0, stream>>>(logits, probs, tokens);
}

// Round 3
// 507.455 us; speedup vs baseline: 2.7543x; 1.4039x over previous
//
#include <hip/hip_runtime.h>
#include <stdint.h>
#include <math.h>

// Problem constants
#define MM 256          // B*S = 32*8
#define KD 1024         // D
#define K2 2048         // combined K (real|imag)
#define VV 50257        // vocab

static constexpr size_t OUT_LOGITS = 0;
static constexpr size_t OUT_TOKENS = (size_t)MM * VV;            // 12865792
static constexpr size_t OUT_PROBS  = OUT_TOKENS + MM;            // 12866048
static constexpr size_t OUT_LOGPR  = OUT_PROBS + (size_t)MM * VV;// 25731840

// ws layout: [0, 2MB) packed A ; [2MB, +2KB) row stats
#define WS_ABUF_BYTES (2u * 1024u * 1024u)

typedef __attribute__((ext_vector_type(8))) short bf16x8;
typedef __attribute__((ext_vector_type(4))) float f32x4;

// ---------------- bf16 split helpers --------------------------------------
__device__ __forceinline__ ushort f2bf(float x) {
  unsigned u = __float_as_uint(x);
  unsigned r = u + 0x7FFFu + ((u >> 16) & 1u);   // RNE
  return (ushort)(r >> 16);
}
__device__ __forceinline__ float bf2f(ushort h) {
  return __uint_as_float(((unsigned)h) << 16);
}

// ---------------- Threefry-2x32-20 (JAX-compatible) ----------------
__device__ __forceinline__ unsigned rotl32(unsigned x, int r) {
  return (x << r) | (x >> (32 - r));
}

__device__ __forceinline__ uint2 threefry2x32(unsigned k0, unsigned k1,
                                              unsigned x0, unsigned x1) {
  unsigned ks[3] = {k0, k1, k0 ^ k1 ^ 0x1BD11BDAu};
  const int rot[8] = {13, 15, 26, 6, 17, 29, 16, 24};
  x0 += ks[0]; x1 += ks[1];
  #pragma unroll
  for (int g = 0; g < 5; ++g) {
    const int base = (g & 1) ? 4 : 0;
    #pragma unroll
    for (int i = 0; i < 4; ++i) {
      x0 += x1;
      x1 = rotl32(x1, rot[base + i]);
      x1 ^= x0;
    }
    x0 += ks[(g + 1) % 3];
    x1 += ks[(g + 2) % 3] + (unsigned)(g + 1);
  }
  return make_uint2(x0, x1);
}

__device__ __forceinline__ float gumbel_at(unsigned flat) {
  uint2 r = threefry2x32(0u, 42u, 0u, flat);
  unsigned w = r.x ^ r.y;
  unsigned fb = (w >> 9) | 0x3F800000u;
  float f = __uint_as_float(fb) - 1.0f;
  const float tiny = 1.1754943508222875e-38f;
  float u = fmaxf(tiny, f + tiny);
  float t1 = (float)log((double)u);
  float t3 = (float)log((double)(-t1));
  return -t3;
}

// ---------------- K0: pack psi -> hi/lo bf16 in MFMA fragment layout ------
// chunk c = (s*16 + mb)*2 + h ; each chunk = 64 lanes x 8 shorts = 1KB.
// s in [0,64): k-slice of 32 (s<32 -> psi_r, else psi_i). mb: m-block of 16.
// lane l: lr=l&15 (row within block), lg=l>>4 (k-group of 8).
__global__ __launch_bounds__(256)
void k_prep(const float* __restrict__ psi_r, const float* __restrict__ psi_i,
            ushort* __restrict__ a_buf) {
  int t = blockIdx.x * 256 + threadIdx.x;   // 65536 threads: (s, mb, lane)
  int lane = t & 63;
  int mb = (t >> 6) & 15;
  int s = t >> 10;                          // 0..63
  int lr = lane & 15, lg = lane >> 4;
  int m = mb * 16 + lr;
  int kloc = (s & 31) * 32 + lg * 8;
  const float* __restrict__ src = (s < 32) ? psi_r : psi_i;
  float4 v0 = *reinterpret_cast<const float4*>(&src[m * KD + kloc]);
  float4 v1 = *reinterpret_cast<const float4*>(&src[m * KD + kloc + 4]);
  float in[8] = {v0.x, v0.y, v0.z, v0.w, v1.x, v1.y, v1.z, v1.w};
  ushort h[8], l[8];
  #pragma unroll
  for (int j = 0; j < 8; ++j) {
    h[j] = f2bf(in[j]);
    l[j] = f2bf(in[j] - bf2f(h[j]));
  }
  size_t base = ((size_t)(s * 16 + mb) * 2) * 512 + (size_t)lane * 8;
  #pragma unroll
  for (int j = 0; j < 8; ++j) {
    a_buf[base + j] = h[j];
    a_buf[base + 512 + j] = l[j];
  }
}

// ---------------- K1: split-bf16 MFMA GEMM --------------------------------
#define BM 256
#define BN 64
#define BK 64
#define GT 512

__global__ __launch_bounds__(GT, 4)
void k_gemm(const uint4* __restrict__ a_buf,
            const float* __restrict__ Wr, const float* __restrict__ Wi,
            const float* __restrict__ bias, float* __restrict__ logits) {
  __shared__ ushort sB[2][2][BN * BK];   // [buf][h][r*64+k], 32 KB

  const int tid  = threadIdx.x;
  const int lane = tid & 63;
  const int wid  = tid >> 6;    // 0..7
  const int wm   = wid >> 1;    // 0..3  -> m block of 64
  const int wn   = wid & 1;     // 0..1  -> n block of 32
  const int vb   = blockIdx.x * BN;

  const int lr = lane & 15;
  const int lg = lane >> 4;

  f32x4 acc[4][2];
  #pragma unroll
  for (int i = 0; i < 4; ++i)
    #pragma unroll
    for (int j = 0; j < 2; ++j)
      #pragma unroll
      for (int q = 0; q < 4; ++q) acc[i][j][q] = 0.f;

  // B staging coords: 8 threads per row, 8 f32 per thread
  const int brow = tid >> 3;          // 0..63
  const int bc8  = (tid & 7) * 8;     // 0..56
  const int gn   = vb + brow;

  float4 b0, b1;
  {
    b0 = make_float4(0.f, 0.f, 0.f, 0.f);
    b1 = b0;
    if (gn < VV) {
      b0 = *reinterpret_cast<const float4*>(&Wr[(size_t)gn * KD + bc8]);
      b1 = *reinterpret_cast<const float4*>(&Wr[(size_t)gn * KD + bc8 + 4]);
    }
  }

  int cur = 0;
  for (int s2 = 0; s2 < K2 / BK; ++s2) {   // 32 steps
    // convert current tile, write to LDS buf[cur]
    {
      float in[8] = {b0.x, b0.y, b0.z, b0.w, b1.x, b1.y, b1.z, b1.w};
      ushort h[8], l[8];
      #pragma unroll
      for (int j = 0; j < 8; ++j) {
        h[j] = f2bf(in[j]);
        l[j] = f2bf(in[j] - bf2f(h[j]));
      }
      int eoff = (brow * BK + bc8) ^ ((brow & 7) << 3);
      *reinterpret_cast<uint4*>(&sB[cur][0][eoff]) =
          make_uint4((unsigned)h[0] | ((unsigned)h[1] << 16),
                     (unsigned)h[2] | ((unsigned)h[3] << 16),
                     (unsigned)h[4] | ((unsigned)h[5] << 16),
                     (unsigned)h[6] | ((unsigned)h[7] << 16));
      *reinterpret_cast<uint4*>(&sB[cur][1][eoff]) =
          make_uint4((unsigned)l[0] | ((unsigned)l[1] << 16),
                     (unsigned)l[2] | ((unsigned)l[3] << 16),
                     (unsigned)l[4] | ((unsigned)l[5] << 16),
                     (unsigned)l[6] | ((unsigned)l[7] << 16));
    }
    // prefetch next B tile (stays in flight across the barrier)
    if (s2 < K2 / BK - 1) {
      int kk = (s2 + 1) * BK;
      const float* __restrict__ Bs = (kk < KD) ? Wr : Wi;
      int ko = kk & (KD - 1);
      if (gn < VV) {
        b0 = *reinterpret_cast<const float4*>(&Bs[(size_t)gn * KD + ko + bc8]);
        b1 = *reinterpret_cast<const float4*>(&Bs[(size_t)gn * KD + ko + bc8 + 4]);
      }
    }
    __syncthreads();

    #pragma unroll
    for (int kq = 0; kq < 2; ++kq) {
      const int s = s2 * 2 + kq;
      // B fragments from LDS
      bf16x8 bh[2], bl[2];
      #pragma unroll
      for (int ni = 0; ni < 2; ++ni) {
        int r = wn * 32 + ni * 16 + lr;
        int eoff = (r * BK + kq * 32 + lg * 8) ^ ((r & 7) << 3);
        bh[ni] = *reinterpret_cast<const bf16x8*>(&sB[cur][0][eoff]);
        bl[ni] = *reinterpret_cast<const bf16x8*>(&sB[cur][1][eoff]);
      }
      // A fragments direct from global (L2-resident packed buffer)
      bf16x8 ah[4], al[4];
      #pragma unroll
      for (int mi = 0; mi < 4; ++mi) {
        int chunk2 = (s * 16 + wm * 4 + mi) * 2;   // h=0 chunk index
        uint4 va = a_buf[(size_t)chunk2 * 64 + lane];
        uint4 vb2 = a_buf[(size_t)(chunk2 + 1) * 64 + lane];
        ah[mi] = *reinterpret_cast<bf16x8*>(&va);
        al[mi] = *reinterpret_cast<bf16x8*>(&vb2);
      }
      #pragma unroll
      for (int mi = 0; mi < 4; ++mi) {
        #pragma unroll
        for (int ni = 0; ni < 2; ++ni) {
          acc[mi][ni] = __builtin_amdgcn_mfma_f32_16x16x32_bf16(ah[mi], bh[ni], acc[mi][ni], 0, 0, 0);
          acc[mi][ni] = __builtin_amdgcn_mfma_f32_16x16x32_bf16(al[mi], bh[ni], acc[mi][ni], 0, 0, 0);
          acc[mi][ni] = __builtin_amdgcn_mfma_f32_16x16x32_bf16(ah[mi], bl[ni], acc[mi][ni], 0, 0, 0);
        }
      }
    }
    cur ^= 1;
  }

  // epilogue: D layout col=lane&15, row=(lane>>4)*4+reg
  #pragma unroll
  for (int ni = 0; ni < 2; ++ni) {
    int v = vb + wn * 32 + ni * 16 + lr;
    if (v < VV) {
      float b = bias[v];
      #pragma unroll
      for (int mi = 0; mi < 4; ++mi) {
        #pragma unroll
        for (int j = 0; j < 4; ++j) {
          int m = wm * 64 + mi * 16 + lg * 4 + j;
          logits[(size_t)m * VV + v] = acc[mi][ni][j] + b;
        }
      }
    }
  }
}

// ---------------- K2: per-row max & log-sum-exp --------------------------
#define NF4 (VV / 4)     // 12564, covers 50256; elem 50256 is the tail

__global__ __launch_bounds__(512)
void k_rowstats(const float* __restrict__ logits, float* __restrict__ ws) {
  const int row = blockIdx.x;
  const float* __restrict__ x = logits + (size_t)row * VV;
  float lm = -INFINITY, ls = 0.f;
  for (int i4 = threadIdx.x; i4 < NF4; i4 += 512) {
    float4 v4 = *reinterpret_cast<const float4*>(&x[i4 * 4]);
    float vs[4] = {v4.x, v4.y, v4.z, v4.w};
    #pragma unroll
    for (int j = 0; j < 4; ++j) {
      float v = vs[j];
      if (v <= lm) {
        ls += expf(v - lm);
      } else {
        ls = ls * expf(lm - v) + 1.f;
        lm = v;
      }
    }
  }
  if (threadIdx.x == 0) {   // tail element
    float v = x[VV - 1];
    if (v <= lm) ls += expf(v - lm);
    else { ls = ls * expf(lm - v) + 1.f; lm = v; }
  }
  __shared__ float sm[512], ss[512];
  sm[threadIdx.x] = lm;
  ss[threadIdx.x] = ls;
  __syncthreads();
  for (int off = 256; off > 0; off >>= 1) {
    if (threadIdx.x < off) {
      float m1 = sm[threadIdx.x], s1 = ss[threadIdx.x];
      float m2 = sm[threadIdx.x + off], s2 = ss[threadIdx.x + off];
      float m = fmaxf(m1, m2);
      ss[threadIdx.x] = s1 * expf(m1 - m) + s2 * expf(m2 - m);
      sm[threadIdx.x] = m;
    }
    __syncthreads();
  }
  if (threadIdx.x == 0) {
    ws[row * 2 + 0] = sm[0];
    ws[row * 2 + 1] = logf(ss[0]);
  }
}

// ---------------- K3: log_probs + zero probs chunk -----------------------
#define ROWQ (NF4 + 1)   // 12565 quad-slots per row (last is the 1-elem tail)

__global__ __launch_bounds__(256)
void k_logprobs(const float* __restrict__ logits, const float* __restrict__ ws,
                float* __restrict__ logpr, float* __restrict__ probs) {
  const int totq = MM * ROWQ;
  for (int q = blockIdx.x * blockDim.x + threadIdx.x; q < totq;
       q += gridDim.x * blockDim.x) {
    unsigned row = (unsigned)q / (unsigned)ROWQ;   // constant divisor -> magic mul
    unsigned c = (unsigned)q - row * ROWQ;
    float mx = ws[row * 2 + 0], lz = ws[row * 2 + 1];
    size_t base = (size_t)row * VV;
    if (c < NF4) {
      size_t idx = base + c * 4;
      float4 v = *reinterpret_cast<const float4*>(&logits[idx]);
      *reinterpret_cast<float4*>(&logpr[idx]) =
          make_float4((v.x - mx) - lz, (v.y - mx) - lz,
                      (v.z - mx) - lz, (v.w - mx) - lz);
      *reinterpret_cast<float4*>(&probs[idx]) = make_float4(0.f, 0.f, 0.f, 0.f);
    } else {
      size_t idx = base + VV - 1;
      logpr[idx] = (logits[idx] - mx) - lz;
      probs[idx] = 0.f;
    }
  }
}

// ---------------- K4: top-k/top-p filter, probs scatter, token sample ----
#define CAP 1024
#define ST 512

__device__ __forceinline__ unsigned ordf(float f) {
  unsigned u = __float_as_uint(f);
  return u ^ ((u >> 31) ? 0xFFFFFFFFu : 0x80000000u);
}

__global__ __launch_bounds__(ST)
void k_sample(const float* __restrict__ logits, float* __restrict__ probs,
              float* __restrict__ tokens) {
  const int row = blockIdx.x;
  const int tid = threadIdx.x;
  const float* __restrict__ x = logits + (size_t)row * VV;

  __shared__ unsigned hist[4096];
  __shared__ float cv[CAP];
  __shared__ int   ci[CAP];
  __shared__ unsigned s_cnt;
  __shared__ unsigned s_lo;
  __shared__ float top_v[50];
  __shared__ int   top_i[50];

  for (int i = tid; i < 4096; i += ST) hist[i] = 0u;
  __syncthreads();

  for (int i4 = tid; i4 < NF4; i4 += ST) {
    float4 v = *reinterpret_cast<const float4*>(&x[i4 * 4]);
    atomicAdd(&hist[ordf(v.x) >> 20], 1u);
    atomicAdd(&hist[ordf(v.y) >> 20], 1u);
    atomicAdd(&hist[ordf(v.z) >> 20], 1u);
    atomicAdd(&hist[ordf(v.w) >> 20], 1u);
  }
  if (tid == 0) atomicAdd(&hist[ordf(x[VV - 1]) >> 20], 1u);
  __syncthreads();

  if (tid == 0) {
    unsigned cum = 0;
    int bin = 0;
    for (int b = 4095; b >= 0; --b) {
      cum += hist[b];
      if (cum >= 50u) { bin = b; break; }
    }
    s_lo = (unsigned)bin << 20;
    s_cnt = 0u;
  }
  __syncthreads();

  const unsigned lo = s_lo;
  for (int i4 = tid; i4 < NF4; i4 += ST) {
    float4 v = *reinterpret_cast<const float4*>(&x[i4 * 4]);
    float vs[4] = {v.x, v.y, v.z, v.w};
    #pragma unroll
    for (int j = 0; j < 4; ++j) {
      if (ordf(vs[j]) >= lo) {
        unsigned pos = atomicAdd(&s_cnt, 1u);
        if (pos < CAP) { cv[pos] = vs[j]; ci[pos] = i4 * 4 + j; }
      }
    }
  }
  if (tid == 0) {
    float v = x[VV - 1];
    if (ordf(v) >= lo) {
      unsigned pos = atomicAdd(&s_cnt, 1u);
      if (pos < CAP) { cv[pos] = v; ci[pos] = VV - 1; }
    }
  }
  __syncthreads();
  const int ncand = (int)min(s_cnt, (unsigned)CAP);

  // single-wave 50-round argmax (value desc, index asc) — no barriers
  if (tid < 64) {
    for (int it = 0; it < 50; ++it) {
      float bv = -INFINITY;
      int bi = 0x7FFFFFFF, bs = 0;
      for (int c = tid; c < ncand; c += 64) {
        float v = cv[c];
        int id = ci[c];
        if (v > bv || (v == bv && id < bi)) { bv = v; bi = id; bs = c; }
      }
      #pragma unroll
      for (int off = 32; off > 0; off >>= 1) {
        float ov = __shfl_xor(bv, off);
        int oi = __shfl_xor(bi, off);
        int os = __shfl_xor(bs, off);
        if (ov > bv || (ov == bv && oi < bi)) { bv = ov; bi = oi; bs = os; }
      }
      if (tid == 0) {
        top_v[it] = bv;
        top_i[it] = bi;
        cv[bs] = -INFINITY;   // same-wave LDS ops are in-order: visible next round
      }
    }
  }

  if (tid == 0) {
    float mx = top_v[0];
    float sp[50];
    float Z = 0.f;
    for (int i = 0; i < 50; ++i) { sp[i] = expf(top_v[i] - mx); Z += sp[i]; }
    float cum = 0.f, Z2 = 0.f;
    int nkeep = 0;
    for (int i = 0; i < 50; ++i) {
      bool keep = (i == 0) || (cum < 0.95f);
      if (!keep) break;
      nkeep = i + 1;
      Z2 += sp[i];
      cum += sp[i] / Z;
    }
    float bestval = -INFINITY;
    int besttok = 0x7FFFFFFF;
    for (int i = 0; i < nkeep; ++i) {
      int idx = top_i[i];
      probs[(size_t)row * VV + idx] = sp[i] / Z2;
      unsigned flat = (unsigned)(row * VV + idx);
      float t = top_v[i] + gumbel_at(flat);
      if (t > bestval || (t == bestval && idx < besttok)) {
        bestval = t; besttok = idx;
      }
    }
    tokens[row] = (float)besttok;
  }
}

// ---------------- launch --------------------------------------------------
extern "C" void kernel_launch(void* const* d_in, const int* in_sizes, int n_in,
                              void* d_out, int out_size, void* d_ws, size_t ws_size,
                              hipStream_t stream) {
  const float* psi_r = (const float*)d_in[0];
  const float* psi_i = (const float*)d_in[1];
  const float* Wr    = (const float*)d_in[2];
  const float* Wi    = (const float*)d_in[3];
  const float* bias  = (const float*)d_in[4];
  float* out = (float*)d_out;

  ushort* a_buf = (ushort*)d_ws;
  float* stats  = (float*)((char*)d_ws + WS_ABUF_BYTES);

  float* logits = out + OUT_LOGITS;
  float* tokens = out + OUT_TOKENS;
  float* probs  = out + OUT_PROBS;
  float* logpr  = out + OUT_LOGPR;

  k_prep<<<256, 256, 0, stream>>>(psi_r, psi_i, a_buf);
  const int nblk = (VV + BN - 1) / BN;  // 786
  k_gemm<<<nblk, GT, 0, stream>>>((const uint4*)a_buf, Wr, Wi, bias, logits);
  k_rowstats<<<MM, 512, 0, stream>>>(logits, stats);
  k_logprobs<<<3072, 256, 0, stream>>>(logits, stats, logpr, probs);
  k_sample<<<MM, ST, 0, stream>>>(logits, probs, tokens);
}

// Round 4
// 350.090 us; speedup vs baseline: 3.9923x; 1.4495x over previous
//
#include <hip/hip_runtime.h>
#include <stdint.h>
#include <math.h>

// Problem constants
#define MM 256          // B*S = 32*8
#define KD 1024         // D
#define K2 2048         // combined K (real|imag)
#define VV 50257        // vocab
#define NF4 (VV / 4)    // 12564 float4 slots; elem 50256 is the tail
#define ROWQ (NF4 + 1)

static constexpr size_t OUT_TOKENS = (size_t)MM * VV;            // 12865792
static constexpr size_t OUT_PROBS  = OUT_TOKENS + MM;            // 12866048
static constexpr size_t OUT_LOGPR  = OUT_PROBS + (size_t)MM * VV;// 25731840

// ws layout: [0, 2MB) packed A ; [2MB, +4KB) row stats (4 f32/row)
#define WS_ABUF_BYTES (2u * 1024u * 1024u)

typedef __attribute__((ext_vector_type(8))) short bf16x8;
typedef __attribute__((ext_vector_type(4))) float f32x4;

// ---------------- bf16 split helpers --------------------------------------
__device__ __forceinline__ ushort f2bf(float x) {
  unsigned u = __float_as_uint(x);
  unsigned r = u + 0x7FFFu + ((u >> 16) & 1u);   // RNE
  return (ushort)(r >> 16);
}
__device__ __forceinline__ float bf2f(ushort h) {
  return __uint_as_float(((unsigned)h) << 16);
}

// ---------------- Threefry-2x32-20 (JAX-compatible) ----------------
__device__ __forceinline__ unsigned rotl32(unsigned x, int r) {
  return (x << r) | (x >> (32 - r));
}

__device__ __forceinline__ uint2 threefry2x32(unsigned k0, unsigned k1,
                                              unsigned x0, unsigned x1) {
  unsigned ks[3] = {k0, k1, k0 ^ k1 ^ 0x1BD11BDAu};
  const int rot[8] = {13, 15, 26, 6, 17, 29, 16, 24};
  x0 += ks[0]; x1 += ks[1];
  #pragma unroll
  for (int g = 0; g < 5; ++g) {
    const int base = (g & 1) ? 4 : 0;
    #pragma unroll
    for (int i = 0; i < 4; ++i) {
      x0 += x1;
      x1 = rotl32(x1, rot[base + i]);
      x1 ^= x0;
    }
    x0 += ks[(g + 1) % 3];
    x1 += ks[(g + 2) % 3] + (unsigned)(g + 1);
  }
  return make_uint2(x0, x1);
}

__device__ __forceinline__ float gumbel_at(unsigned flat) {
  uint2 r = threefry2x32(0u, 42u, 0u, flat);
  unsigned w = r.x ^ r.y;
  unsigned fb = (w >> 9) | 0x3F800000u;
  float f = __uint_as_float(fb) - 1.0f;
  const float tiny = 1.1754943508222875e-38f;
  float u = fmaxf(tiny, f + tiny);
  float t1 = (float)log((double)u);
  float t3 = (float)log((double)(-t1));
  return -t3;
}

// ---------------- K0: pack psi -> hi/lo bf16 in MFMA fragment layout ------
// chunk c = (s*16 + mb)*2 + h ; each chunk = 64 lanes x 8 shorts = 1KB.
__global__ __launch_bounds__(256)
void k_prep(const float* __restrict__ psi_r, const float* __restrict__ psi_i,
            ushort* __restrict__ a_buf) {
  int t = blockIdx.x * 256 + threadIdx.x;   // 65536 threads: (s, mb, lane)
  int lane = t & 63;
  int mb = (t >> 6) & 15;
  int s = t >> 10;                          // 0..63
  int lr = lane & 15, lg = lane >> 4;
  int m = mb * 16 + lr;
  int kloc = (s & 31) * 32 + lg * 8;
  const float* __restrict__ src = (s < 32) ? psi_r : psi_i;
  float4 v0 = *reinterpret_cast<const float4*>(&src[m * KD + kloc]);
  float4 v1 = *reinterpret_cast<const float4*>(&src[m * KD + kloc + 4]);
  float in[8] = {v0.x, v0.y, v0.z, v0.w, v1.x, v1.y, v1.z, v1.w};
  ushort h[8], l[8];
  #pragma unroll
  for (int j = 0; j < 8; ++j) {
    h[j] = f2bf(in[j]);
    l[j] = f2bf(in[j] - bf2f(h[j]));
  }
  size_t base = ((size_t)(s * 16 + mb) * 2) * 512 + (size_t)lane * 8;
  #pragma unroll
  for (int j = 0; j < 8; ++j) {
    a_buf[base + j] = h[j];
    a_buf[base + 512 + j] = l[j];
  }
}

// ---------------- K1: split-bf16 MFMA GEMM, BN=32 -------------------------
#define BN 32
#define BK 64
#define GT 512

__global__ __launch_bounds__(GT, 4)
void k_gemm(const uint4* __restrict__ a_buf,
            const float* __restrict__ Wr, const float* __restrict__ Wi,
            const float* __restrict__ bias, float* __restrict__ logits) {
  __shared__ ushort sBh[2][BN * BK];   // 4 KB each buf
  __shared__ ushort sBl[2][BN * BK];

  const int tid  = threadIdx.x;
  const int lane = tid & 63;
  const int wid  = tid >> 6;    // 0..7 -> m block of 32
  const int vb   = blockIdx.x * BN;
  const int lr = lane & 15;
  const int lg = lane >> 4;

  // B staging coords: 16 threads per row, 4 f32 per thread
  const int brow = tid >> 4;          // 0..31
  const int bc4  = (tid & 15) << 2;   // 0..60
  const int gn   = vb + brow;
  const int eoW  = brow * BK + (bc4 ^ ((brow & 7) << 3));

  f32x4 acc[2][2];
  #pragma unroll
  for (int i = 0; i < 2; ++i)
    #pragma unroll
    for (int j = 0; j < 2; ++j)
      #pragma unroll
      for (int q = 0; q < 4; ++q) acc[i][j][q] = 0.f;

  float4 w = make_float4(0.f, 0.f, 0.f, 0.f);
  if (gn < VV) w = *reinterpret_cast<const float4*>(&Wr[(size_t)gn * KD + bc4]);

  int cur = 0;
  for (int s2 = 0; s2 < K2 / BK; ++s2) {   // 32 steps
    // ---- issue ALL A loads for this step first (latency hidden by staging+barrier)
    uint4 vah[2][2], val[2][2];   // [kq][mi]
    #pragma unroll
    for (int kq = 0; kq < 2; ++kq) {
      #pragma unroll
      for (int mi = 0; mi < 2; ++mi) {
        int chunk2 = (((s2 * 2 + kq) * 16) + wid * 2 + mi) * 2;
        vah[kq][mi] = a_buf[(size_t)chunk2 * 64 + lane];
        val[kq][mi] = a_buf[(size_t)(chunk2 + 1) * 64 + lane];
      }
    }
    // ---- convert current W regs, write LDS[cur]
    {
      float in[4] = {w.x, w.y, w.z, w.w};
      ushort h[4], l[4];
      #pragma unroll
      for (int j = 0; j < 4; ++j) {
        h[j] = f2bf(in[j]);
        l[j] = f2bf(in[j] - bf2f(h[j]));
      }
      *reinterpret_cast<uint2*>(&sBh[cur][eoW]) =
          make_uint2((unsigned)h[0] | ((unsigned)h[1] << 16),
                     (unsigned)h[2] | ((unsigned)h[3] << 16));
      *reinterpret_cast<uint2*>(&sBl[cur][eoW]) =
          make_uint2((unsigned)l[0] | ((unsigned)l[1] << 16),
                     (unsigned)l[2] | ((unsigned)l[3] << 16));
    }
    // ---- prefetch next W tile
    if (s2 < K2 / BK - 1) {
      int kk = (s2 + 1) * BK;
      const float* __restrict__ Bs = (kk < KD) ? Wr : Wi;
      int ko = kk & (KD - 1);
      if (gn < VV)
        w = *reinterpret_cast<const float4*>(&Bs[(size_t)gn * KD + ko + bc4]);
    }
    __syncthreads();

    // ---- compute: A already in registers, B from LDS
    #pragma unroll
    for (int kq = 0; kq < 2; ++kq) {
      bf16x8 bh[2], bl[2];
      #pragma unroll
      for (int ni = 0; ni < 2; ++ni) {
        int r = ni * 16 + lr;
        int eoff = r * BK + ((kq * 32 + lg * 8) ^ ((r & 7) << 3));
        bh[ni] = *reinterpret_cast<const bf16x8*>(&sBh[cur][eoff]);
        bl[ni] = *reinterpret_cast<const bf16x8*>(&sBl[cur][eoff]);
      }
      #pragma unroll
      for (int mi = 0; mi < 2; ++mi) {
        bf16x8 ah = *reinterpret_cast<bf16x8*>(&vah[kq][mi]);
        bf16x8 al = *reinterpret_cast<bf16x8*>(&val[kq][mi]);
        #pragma unroll
        for (int ni = 0; ni < 2; ++ni) {
          acc[mi][ni] = __builtin_amdgcn_mfma_f32_16x16x32_bf16(ah, bh[ni], acc[mi][ni], 0, 0, 0);
          acc[mi][ni] = __builtin_amdgcn_mfma_f32_16x16x32_bf16(al, bh[ni], acc[mi][ni], 0, 0, 0);
          acc[mi][ni] = __builtin_amdgcn_mfma_f32_16x16x32_bf16(ah, bl[ni], acc[mi][ni], 0, 0, 0);
        }
      }
    }
    cur ^= 1;
  }

  // epilogue: D layout col=lane&15, row=(lane>>4)*4+reg
  #pragma unroll
  for (int ni = 0; ni < 2; ++ni) {
    int n = vb + ni * 16 + lr;
    if (n < VV) {
      float b = bias[n];
      #pragma unroll
      for (int mi = 0; mi < 2; ++mi) {
        #pragma unroll
        for (int j = 0; j < 4; ++j) {
          int m = wid * 32 + mi * 16 + lg * 4 + j;
          logits[(size_t)m * VV + n] = acc[mi][ni][j] + b;
        }
      }
    }
  }
}

// ---------------- K2: fused row stats (max, lse) + top-50 threshold -------
__device__ __forceinline__ unsigned ordf(float f) {
  unsigned u = __float_as_uint(f);
  return u ^ ((u >> 31) ? 0xFFFFFFFFu : 0x80000000u);
}

__global__ __launch_bounds__(1024)
void k_stats(const float* __restrict__ logits, float* __restrict__ ws4) {
  const int row = blockIdx.x;
  const int tid = threadIdx.x;
  const float* __restrict__ x = logits + (size_t)row * VV;

  __shared__ unsigned hist[4096];
  __shared__ float pm[16], ps[16];

  for (int i = tid; i < 4096; i += 1024) hist[i] = 0u;
  __syncthreads();

  float lm = -INFINITY, ls = 0.f;
  for (int i4 = tid; i4 < NF4; i4 += 1024) {
    float4 v4 = *reinterpret_cast<const float4*>(&x[i4 * 4]);
    float vs[4] = {v4.x, v4.y, v4.z, v4.w};
    #pragma unroll
    for (int j = 0; j < 4; ++j) {
      float v = vs[j];
      atomicAdd(&hist[ordf(v) >> 20], 1u);
      if (v <= lm) {
        ls += expf(v - lm);
      } else {
        ls = ls * expf(lm - v) + 1.f;
        lm = v;
      }
    }
  }
  if (tid == 0) {   // tail element
    float v = x[VV - 1];
    atomicAdd(&hist[ordf(v) >> 20], 1u);
    if (v <= lm) ls += expf(v - lm);
    else { ls = ls * expf(lm - v) + 1.f; lm = v; }
  }
  // wave-level (m,s) reduce
  #pragma unroll
  for (int off = 32; off; off >>= 1) {
    float om = __shfl_xor(lm, off);
    float os = __shfl_xor(ls, off);
    float M = fmaxf(lm, om);
    ls = ls * expf(lm - M) + os * expf(om - M);
    lm = M;
  }
  if ((tid & 63) == 0) { pm[tid >> 6] = lm; ps[tid >> 6] = ls; }
  __syncthreads();

  if (tid < 64) {
    // merge 16 wave partials (lanes >=16 use finite identity to avoid NaN)
    float m2 = (tid < 16) ? pm[tid] : -3e38f;
    float s2 = (tid < 16) ? ps[tid] : 0.f;
    #pragma unroll
    for (int off = 8; off; off >>= 1) {
      float om = __shfl_xor(m2, off);
      float os = __shfl_xor(s2, off);
      float M = fmaxf(m2, om);
      s2 = s2 * expf(m2 - M) + os * expf(om - M);
      m2 = M;
    }
    // segment sums of hist: lane l owns bins [l*64, l*64+64) (rotated reads)
    unsigned seg = 0;
    #pragma unroll 8
    for (int b = 0; b < 64; ++b) seg += hist[tid * 64 + ((b + tid) & 63)];
    // suffix scan: suf[l] = sum_{j>=l} seg[j]
    unsigned suf = seg;
    #pragma unroll
    for (int off = 1; off < 64; off <<= 1) {
      unsigned o = __shfl_down(suf, off);
      if (tid + off < 64) suf += o;
    }
    unsigned long long mk = __ballot(suf >= 50u);
    int lstar = 63 - __builtin_clzll(mk);       // highest segment with suffix>=50
    unsigned above = (lstar < 63) ? (unsigned)__shfl((int)suf, lstar + 1) : 0u;
    if (tid == 0) {
      unsigned cum = above;
      int bin = lstar * 64;
      for (int b = 63; b >= 0; --b) {
        cum += hist[lstar * 64 + b];
        if (cum >= 50u) { bin = lstar * 64 + b; break; }
      }
      ws4[row * 4 + 0] = m2;
      ws4[row * 4 + 1] = logf(s2);
      ws4[row * 4 + 2] = __uint_as_float((unsigned)bin << 20);
    }
  }
}

// ---------------- K3: log_probs -------------------------------------------
__global__ __launch_bounds__(1024)
void k_logprobs(const float* __restrict__ logits, const float* __restrict__ ws4,
                float* __restrict__ logpr) {
  const int totq = MM * ROWQ;
  for (int q = blockIdx.x * blockDim.x + threadIdx.x; q < totq;
       q += gridDim.x * blockDim.x) {
    unsigned row = (unsigned)q / (unsigned)ROWQ;   // magic mul
    unsigned c = (unsigned)q - row * ROWQ;
    float mx = ws4[row * 4 + 0], lz = ws4[row * 4 + 1];
    size_t base = (size_t)row * VV;
    if (c < NF4) {
      size_t idx = base + c * 4;
      float4 v = *reinterpret_cast<const float4*>(&logits[idx]);
      *reinterpret_cast<float4*>(&logpr[idx]) =
          make_float4((v.x - mx) - lz, (v.y - mx) - lz,
                      (v.z - mx) - lz, (v.w - mx) - lz);
    } else {
      size_t idx = base + VV - 1;
      logpr[idx] = (logits[idx] - mx) - lz;
    }
  }
}

// ---------------- K4: collect + top-k/top-p + probs scatter + token -------
#define CAP 1024

__global__ __launch_bounds__(1024)
void k_collect(const float* __restrict__ logits, const float* __restrict__ ws4,
               float* __restrict__ probs, float* __restrict__ tokens) {
  const int row = blockIdx.x;
  const int tid = threadIdx.x;
  const float* __restrict__ x = logits + (size_t)row * VV;

  __shared__ float cv[CAP];
  __shared__ int   ci[CAP];
  __shared__ unsigned s_cnt;
  __shared__ float top_v[50];
  __shared__ int   top_i[50];

  if (tid == 0) s_cnt = 0u;
  __syncthreads();

  const unsigned lo = __float_as_uint(ws4[row * 4 + 2]);
  for (int i4 = tid; i4 < NF4; i4 += 1024) {
    float4 v = *reinterpret_cast<const float4*>(&x[i4 * 4]);
    float vs[4] = {v.x, v.y, v.z, v.w};
    #pragma unroll
    for (int j = 0; j < 4; ++j) {
      if (ordf(vs[j]) >= lo) {
        unsigned pos = atomicAdd(&s_cnt, 1u);
        if (pos < CAP) { cv[pos] = vs[j]; ci[pos] = i4 * 4 + j; }
      }
    }
  }
  if (tid == 0) {
    float v = x[VV - 1];
    if (ordf(v) >= lo) {
      unsigned pos = atomicAdd(&s_cnt, 1u);
      if (pos < CAP) { cv[pos] = v; ci[pos] = VV - 1; }
    }
  }
  __syncthreads();
  const int ncand = (int)min(s_cnt, (unsigned)CAP);

  if (tid < 64) {
    // 50-round wave argmax (value desc, index asc)
    for (int it = 0; it < 50; ++it) {
      float bv = -INFINITY;
      int bi = 0x7FFFFFFF, bs = 0;
      for (int c = tid; c < ncand; c += 64) {
        float v = cv[c];
        int id = ci[c];
        if (v > bv || (v == bv && id < bi)) { bv = v; bi = id; bs = c; }
      }
      #pragma unroll
      for (int off = 32; off; off >>= 1) {
        float ov = __shfl_xor(bv, off);
        int oi = __shfl_xor(bi, off);
        int os = __shfl_xor(bs, off);
        if (ov > bv || (ov == bv && oi < bi)) { bv = ov; bi = oi; bs = os; }
      }
      if (tid == 0) {
        top_v[it] = bv;
        top_i[it] = bi;
        cv[bs] = -INFINITY;   // same-wave LDS ops in-order
      }
    }

    // lane-parallel softmax / top-p / gumbel over the 50 survivors
    float tv = (tid < 50) ? top_v[tid] : -3e38f;
    float mx = top_v[0];
    float sp = (tid < 50) ? expf(tv - mx) : 0.f;
    float Z = sp;
    #pragma unroll
    for (int off = 32; off; off >>= 1) Z += __shfl_xor(Z, off);
    float pref = sp;   // inclusive prefix over lane order
    #pragma unroll
    for (int off = 1; off < 64; off <<= 1) {
      float o = __shfl_up(pref, off);
      if (tid >= off) pref += o;
    }
    float excl = (pref - sp) / Z;
    bool keep = (tid < 50) && ((tid == 0) || (excl < 0.95f));
    float spk = keep ? sp : 0.f;
    float Z2 = spk;
    #pragma unroll
    for (int off = 32; off; off >>= 1) Z2 += __shfl_xor(Z2, off);

    float bt = -3e38f;
    int bidx = 0x7FFFFFFF;
    if (keep) {
      int idx = top_i[tid];
      probs[(size_t)row * VV + idx] = sp / Z2;
      bt = tv + gumbel_at((unsigned)((size_t)row * VV + idx));
      bidx = idx;
    }
    #pragma unroll
    for (int off = 32; off; off >>= 1) {
      float ot = __shfl_xor(bt, off);
      int oi = __shfl_xor(bidx, off);
      if (ot > bt || (ot == bt && oi < bidx)) { bt = ot; bidx = oi; }
    }
    if (tid == 0) tokens[row] = (float)bidx;
  }
}

// ---------------- launch --------------------------------------------------
extern "C" void kernel_launch(void* const* d_in, const int* in_sizes, int n_in,
                              void* d_out, int out_size, void* d_ws, size_t ws_size,
                              hipStream_t stream) {
  const float* psi_r = (const float*)d_in[0];
  const float* psi_i = (const float*)d_in[1];
  const float* Wr    = (const float*)d_in[2];
  const float* Wi    = (const float*)d_in[3];
  const float* bias  = (const float*)d_in[4];
  float* out = (float*)d_out;

  ushort* a_buf = (ushort*)d_ws;
  float* ws4    = (float*)((char*)d_ws + WS_ABUF_BYTES);

  float* logits = out;
  float* tokens = out + OUT_TOKENS;
  float* probs  = out + OUT_PROBS;
  float* logpr  = out + OUT_LOGPR;

  k_prep<<<256, 256, 0, stream>>>(psi_r, psi_i, a_buf);
  const int nblk = (VV + BN - 1) / BN;  // 1571
  k_gemm<<<nblk, GT, 0, stream>>>((const uint4*)a_buf, Wr, Wi, bias, logits);
  hipMemsetAsync(probs, 0, (size_t)MM * VV * sizeof(float), stream);
  k_stats<<<MM, 1024, 0, stream>>>(logits, ws4);
  k_logprobs<<<2048, 1024, 0, stream>>>(logits, ws4, logpr);
  k_collect<<<MM, 1024, 0, stream>>>(logits, ws4, probs, tokens);
}

// Round 5
// 287.898 us; speedup vs baseline: 4.8547x; 1.2160x over previous
//
#include <hip/hip_runtime.h>
#include <stdint.h>
#include <math.h>

// Problem constants
#define MM 256          // B*S = 32*8
#define KD 1024         // D
#define K2 2048         // combined K (real|imag)
#define VV 50257        // vocab
#define NF4 (VV / 4)    // 12564 float4 slots; elem 50256 is the tail
#define ROWQ (NF4 + 1)

static constexpr size_t OUT_TOKENS = (size_t)MM * VV;            // 12865792
static constexpr size_t OUT_PROBS  = OUT_TOKENS + MM;            // 12866048
static constexpr size_t OUT_LOGPR  = OUT_PROBS + (size_t)MM * VV;// 25731840

// ws layout: [0, 2MB) packed A ; [2MB, +4KB) row stats (4 f32/row)
#define WS_ABUF_BYTES (2u * 1024u * 1024u)

typedef __attribute__((ext_vector_type(8))) short bf16x8;
typedef __attribute__((ext_vector_type(4))) float f32x4;

// ---------------- bf16 split helpers --------------------------------------
__device__ __forceinline__ ushort f2bf(float x) {
  unsigned u = __float_as_uint(x);
  unsigned r = u + 0x7FFFu + ((u >> 16) & 1u);   // RNE
  return (ushort)(r >> 16);
}
__device__ __forceinline__ float bf2f(ushort h) {
  return __uint_as_float(((unsigned)h) << 16);
}

// ---------------- Threefry-2x32-20 (JAX-compatible) ----------------
__device__ __forceinline__ unsigned rotl32(unsigned x, int r) {
  return (x << r) | (x >> (32 - r));
}

__device__ __forceinline__ uint2 threefry2x32(unsigned k0, unsigned k1,
                                              unsigned x0, unsigned x1) {
  unsigned ks[3] = {k0, k1, k0 ^ k1 ^ 0x1BD11BDAu};
  const int rot[8] = {13, 15, 26, 6, 17, 29, 16, 24};
  x0 += ks[0]; x1 += ks[1];
  #pragma unroll
  for (int g = 0; g < 5; ++g) {
    const int base = (g & 1) ? 4 : 0;
    #pragma unroll
    for (int i = 0; i < 4; ++i) {
      x0 += x1;
      x1 = rotl32(x1, rot[base + i]);
      x1 ^= x0;
    }
    x0 += ks[(g + 1) % 3];
    x1 += ks[(g + 2) % 3] + (unsigned)(g + 1);
  }
  return make_uint2(x0, x1);
}

__device__ __forceinline__ float gumbel_at(unsigned flat) {
  uint2 r = threefry2x32(0u, 42u, 0u, flat);
  unsigned w = r.x ^ r.y;
  unsigned fb = (w >> 9) | 0x3F800000u;
  float f = __uint_as_float(fb) - 1.0f;
  const float tiny = 1.1754943508222875e-38f;
  float u = fmaxf(tiny, f + tiny);
  float t1 = (float)log((double)u);
  float t3 = (float)log((double)(-t1));
  return -t3;
}

// ---------------- K0: pack psi -> hi/lo bf16 in MFMA fragment layout ------
// chunk c = (s*16 + mb)*2 + h ; each chunk = 64 lanes x 8 shorts = 1KB.
__global__ __launch_bounds__(256)
void k_prep(const float* __restrict__ psi_r, const float* __restrict__ psi_i,
            ushort* __restrict__ a_buf) {
  int t = blockIdx.x * 256 + threadIdx.x;   // 65536 threads: (s, mb, lane)
  int lane = t & 63;
  int mb = (t >> 6) & 15;
  int s = t >> 10;                          // 0..63
  int lr = lane & 15, lg = lane >> 4;
  int m = mb * 16 + lr;
  int kloc = (s & 31) * 32 + lg * 8;
  const float* __restrict__ src = (s < 32) ? psi_r : psi_i;
  float4 v0 = *reinterpret_cast<const float4*>(&src[m * KD + kloc]);
  float4 v1 = *reinterpret_cast<const float4*>(&src[m * KD + kloc + 4]);
  float in[8] = {v0.x, v0.y, v0.z, v0.w, v1.x, v1.y, v1.z, v1.w};
  ushort h[8], l[8];
  #pragma unroll
  for (int j = 0; j < 8; ++j) {
    h[j] = f2bf(in[j]);
    l[j] = f2bf(in[j] - bf2f(h[j]));
  }
  size_t base = ((size_t)(s * 16 + mb) * 2) * 512 + (size_t)lane * 8;
  #pragma unroll
  for (int j = 0; j < 8; ++j) {
    a_buf[base + j] = h[j];
    a_buf[base + 512 + j] = l[j];
  }
}

// ---------------- K1: pipelined split-bf16 MFMA GEMM, BN=64 ---------------
#define BN 64
#define BK 64
#define GT 512

__global__ __launch_bounds__(GT, 4)
void k_gemm(const uint4* __restrict__ a_buf,
            const float* __restrict__ Wr, const float* __restrict__ Wi,
            const float* __restrict__ bias, float* __restrict__ logits) {
  __shared__ ushort sBh[2][BN * BK];   // 8 KB per buf
  __shared__ ushort sBl[2][BN * BK];

  const int tid  = threadIdx.x;
  const int lane = tid & 63;
  const int wid  = tid >> 6;    // 0..7 -> m block of 32
  const int vb   = blockIdx.x * BN;
  const int lr = lane & 15;
  const int lg = lane >> 4;

  // B staging coords: 8 threads per row, 8 f32 per thread
  const int brow = tid >> 3;          // 0..63
  const int bc8  = (tid & 7) << 3;    // 0..56
  const int gn   = vb + brow;
  const int eoW  = brow * BK + (bc8 ^ ((brow & 7) << 3));

  f32x4 acc[2][4];
  #pragma unroll
  for (int i = 0; i < 2; ++i)
    #pragma unroll
    for (int j = 0; j < 4; ++j)
      #pragma unroll
      for (int q = 0; q < 4; ++q) acc[i][j][q] = 0.f;

  // prologue: W tile 0 into regs
  float4 wa = make_float4(0.f, 0.f, 0.f, 0.f), wb = wa;
  if (gn < VV) {
    wa = *reinterpret_cast<const float4*>(&Wr[(size_t)gn * KD + bc8]);
    wb = *reinterpret_cast<const float4*>(&Wr[(size_t)gn * KD + bc8 + 4]);
  }

  int cur = 0;
  for (int s2 = 0; s2 < K2 / BK; ++s2) {   // 32 steps
    // ---- issue A loads for THIS step (complete during stage+barrier+dsread)
    uint4 vah[2][2], val[2][2];   // [kq][mi]
    #pragma unroll
    for (int kq = 0; kq < 2; ++kq) {
      #pragma unroll
      for (int mi = 0; mi < 2; ++mi) {
        int chunk2 = (((s2 * 2 + kq) * 16) + wid * 2 + mi) * 2;
        vah[kq][mi] = a_buf[(size_t)chunk2 * 64 + lane];
        val[kq][mi] = a_buf[(size_t)(chunk2 + 1) * 64 + lane];
      }
    }
    // ---- convert W[s2] regs (issued >=1 step ago), write LDS buf[cur]
    {
      float in[8] = {wa.x, wa.y, wa.z, wa.w, wb.x, wb.y, wb.z, wb.w};
      ushort h[8], l[8];
      #pragma unroll
      for (int j = 0; j < 8; ++j) {
        h[j] = f2bf(in[j]);
        l[j] = f2bf(in[j] - bf2f(h[j]));
      }
      *reinterpret_cast<uint4*>(&sBh[cur][eoW]) =
          make_uint4((unsigned)h[0] | ((unsigned)h[1] << 16),
                     (unsigned)h[2] | ((unsigned)h[3] << 16),
                     (unsigned)h[4] | ((unsigned)h[5] << 16),
                     (unsigned)h[6] | ((unsigned)h[7] << 16));
      *reinterpret_cast<uint4*>(&sBl[cur][eoW]) =
          make_uint4((unsigned)l[0] | ((unsigned)l[1] << 16),
                     (unsigned)l[2] | ((unsigned)l[3] << 16),
                     (unsigned)l[4] | ((unsigned)l[5] << 16),
                     (unsigned)l[6] | ((unsigned)l[7] << 16));
    }
    // ---- issue W[s2+1] load AFTER staging-use: stays in flight across barrier
    if (s2 < K2 / BK - 1) {
      int kk = (s2 + 1) * BK;
      const float* __restrict__ Bs = (kk < KD) ? Wr : Wi;
      int ko = kk & (KD - 1);
      if (gn < VV) {
        wa = *reinterpret_cast<const float4*>(&Bs[(size_t)gn * KD + ko + bc8]);
        wb = *reinterpret_cast<const float4*>(&Bs[(size_t)gn * KD + ko + bc8 + 4]);
      }
    }
    // ---- raw barrier: LDS visibility only, NO vmcnt drain
    asm volatile("s_waitcnt lgkmcnt(0)" ::: "memory");
    asm volatile("s_barrier" ::: "memory");

    // ---- compute: B frags from LDS, A from regs (auto vmcnt wait ~ vmcnt(2))
    #pragma unroll
    for (int kq = 0; kq < 2; ++kq) {
      bf16x8 bh[4], bl[4];
      #pragma unroll
      for (int ni = 0; ni < 4; ++ni) {
        int r = ni * 16 + lr;
        int eoff = r * BK + ((kq * 32 + lg * 8) ^ ((r & 7) << 3));
        bh[ni] = *reinterpret_cast<const bf16x8*>(&sBh[cur][eoff]);
        bl[ni] = *reinterpret_cast<const bf16x8*>(&sBl[cur][eoff]);
      }
      #pragma unroll
      for (int mi = 0; mi < 2; ++mi) {
        bf16x8 ah = *reinterpret_cast<bf16x8*>(&vah[kq][mi]);
        bf16x8 al = *reinterpret_cast<bf16x8*>(&val[kq][mi]);
        #pragma unroll
        for (int ni = 0; ni < 4; ++ni) {
          acc[mi][ni] = __builtin_amdgcn_mfma_f32_16x16x32_bf16(ah, bh[ni], acc[mi][ni], 0, 0, 0);
          acc[mi][ni] = __builtin_amdgcn_mfma_f32_16x16x32_bf16(al, bh[ni], acc[mi][ni], 0, 0, 0);
          acc[mi][ni] = __builtin_amdgcn_mfma_f32_16x16x32_bf16(ah, bl[ni], acc[mi][ni], 0, 0, 0);
        }
      }
    }
    cur ^= 1;
  }

  // epilogue: D layout col=lane&15, row=(lane>>4)*4+reg
  #pragma unroll
  for (int ni = 0; ni < 4; ++ni) {
    int n = vb + ni * 16 + lr;
    if (n < VV) {
      float b = bias[n];
      #pragma unroll
      for (int mi = 0; mi < 2; ++mi) {
        #pragma unroll
        for (int j = 0; j < 4; ++j) {
          int m = wid * 32 + mi * 16 + lg * 4 + j;
          logits[(size_t)m * VV + n] = acc[mi][ni][j] + b;
        }
      }
    }
  }
}

// ---------------- K2: fused row stats (max, lse) + top-50 threshold -------
__device__ __forceinline__ unsigned ordf(float f) {
  unsigned u = __float_as_uint(f);
  return u ^ ((u >> 31) ? 0xFFFFFFFFu : 0x80000000u);
}

#define HREP 4
#define HSTRIDE 4097

__global__ __launch_bounds__(1024)
void k_stats(const float* __restrict__ logits, float* __restrict__ ws4) {
  const int row = blockIdx.x;
  const int tid = threadIdx.x;
  const float* __restrict__ x = logits + (size_t)row * VV;

  __shared__ unsigned hist[HREP * HSTRIDE];   // 64 KB + eps
  __shared__ float pm[16], ps[16];

  for (int i = tid; i < HREP * HSTRIDE; i += 1024) hist[i] = 0u;
  __syncthreads();

  const int rep = (tid & 3) * HSTRIDE;
  float lm = -INFINITY, ls = 0.f;
  for (int i4 = tid; i4 < NF4; i4 += 1024) {
    float4 v4 = *reinterpret_cast<const float4*>(&x[i4 * 4]);
    float vs[4] = {v4.x, v4.y, v4.z, v4.w};
    #pragma unroll
    for (int j = 0; j < 4; ++j) {
      float v = vs[j];
      atomicAdd(&hist[rep + (ordf(v) >> 20)], 1u);
      if (v <= lm) {
        ls += expf(v - lm);
      } else {
        ls = ls * expf(lm - v) + 1.f;
        lm = v;
      }
    }
  }
  if (tid == 0) {   // tail element
    float v = x[VV - 1];
    atomicAdd(&hist[ordf(v) >> 20], 1u);
    if (v <= lm) ls += expf(v - lm);
    else { ls = ls * expf(lm - v) + 1.f; lm = v; }
  }
  // wave-level (m,s) reduce
  #pragma unroll
  for (int off = 32; off; off >>= 1) {
    float om = __shfl_xor(lm, off);
    float os = __shfl_xor(ls, off);
    float M = fmaxf(lm, om);
    ls = ls * expf(lm - M) + os * expf(om - M);
    lm = M;
  }
  if ((tid & 63) == 0) { pm[tid >> 6] = lm; ps[tid >> 6] = ls; }
  __syncthreads();

  // merge histogram replicas into replica 0
  for (int b = tid; b < 4096; b += 1024)
    hist[b] = hist[b] + hist[HSTRIDE + b] + hist[2 * HSTRIDE + b] + hist[3 * HSTRIDE + b];
  __syncthreads();

  if (tid < 64) {
    // merge 16 wave partials (lanes >=16 use finite identity to avoid NaN)
    float m2 = (tid < 16) ? pm[tid] : -3e38f;
    float s2 = (tid < 16) ? ps[tid] : 0.f;
    #pragma unroll
    for (int off = 8; off; off >>= 1) {
      float om = __shfl_xor(m2, off);
      float os = __shfl_xor(s2, off);
      float M = fmaxf(m2, om);
      s2 = s2 * expf(m2 - M) + os * expf(om - M);
      m2 = M;
    }
    // segment sums of hist: lane l owns bins [l*64, l*64+64) (rotated reads)
    unsigned seg = 0;
    #pragma unroll 8
    for (int b = 0; b < 64; ++b) seg += hist[tid * 64 + ((b + tid) & 63)];
    // suffix scan: suf[l] = sum_{j>=l} seg[j]
    unsigned suf = seg;
    #pragma unroll
    for (int off = 1; off < 64; off <<= 1) {
      unsigned o = __shfl_down(suf, off);
      if (tid + off < 64) suf += o;
    }
    unsigned long long mk = __ballot(suf >= 50u);
    int lstar = 63 - __builtin_clzll(mk);       // highest segment with suffix>=50
    unsigned above = (lstar < 63) ? (unsigned)__shfl((int)suf, lstar + 1) : 0u;
    if (tid == 0) {
      unsigned cum = above;
      int bin = lstar * 64;
      for (int b = 63; b >= 0; --b) {
        cum += hist[lstar * 64 + b];
        if (cum >= 50u) { bin = lstar * 64 + b; break; }
      }
      ws4[row * 4 + 0] = m2;
      ws4[row * 4 + 1] = logf(s2);
      ws4[row * 4 + 2] = __uint_as_float((unsigned)bin << 20);
    }
  }
}

// ---------------- K3: log_probs + zero probs -------------------------------
__global__ __launch_bounds__(1024)
void k_logprobs(const float* __restrict__ logits, const float* __restrict__ ws4,
                float* __restrict__ logpr, float* __restrict__ probs) {
  const int totq = MM * ROWQ;
  for (int q = blockIdx.x * blockDim.x + threadIdx.x; q < totq;
       q += gridDim.x * blockDim.x) {
    unsigned row = (unsigned)q / (unsigned)ROWQ;   // magic mul
    unsigned c = (unsigned)q - row * ROWQ;
    float mx = ws4[row * 4 + 0], lz = ws4[row * 4 + 1];
    size_t base = (size_t)row * VV;
    if (c < NF4) {
      size_t idx = base + c * 4;
      float4 v = *reinterpret_cast<const float4*>(&logits[idx]);
      *reinterpret_cast<float4*>(&logpr[idx]) =
          make_float4((v.x - mx) - lz, (v.y - mx) - lz,
                      (v.z - mx) - lz, (v.w - mx) - lz);
      *reinterpret_cast<float4*>(&probs[idx]) = make_float4(0.f, 0.f, 0.f, 0.f);
    } else {
      size_t idx = base + VV - 1;
      logpr[idx] = (logits[idx] - mx) - lz;
      probs[idx] = 0.f;
    }
  }
}

// ---------------- K4: collect + top-k/top-p + probs scatter + token -------
#define CAP 1024

__global__ __launch_bounds__(1024)
void k_collect(const float* __restrict__ logits, const float* __restrict__ ws4,
               float* __restrict__ probs, float* __restrict__ tokens) {
  const int row = blockIdx.x;
  const int tid = threadIdx.x;
  const float* __restrict__ x = logits + (size_t)row * VV;

  __shared__ float cv[CAP];
  __shared__ int   ci[CAP];
  __shared__ unsigned s_cnt;
  __shared__ float top_v[50];
  __shared__ int   top_i[50];

  if (tid == 0) s_cnt = 0u;
  __syncthreads();

  const unsigned lo = __float_as_uint(ws4[row * 4 + 2]);
  for (int i4 = tid; i4 < NF4; i4 += 1024) {
    float4 v = *reinterpret_cast<const float4*>(&x[i4 * 4]);
    float vs[4] = {v.x, v.y, v.z, v.w};
    #pragma unroll
    for (int j = 0; j < 4; ++j) {
      if (ordf(vs[j]) >= lo) {
        unsigned pos = atomicAdd(&s_cnt, 1u);
        if (pos < CAP) { cv[pos] = vs[j]; ci[pos] = i4 * 4 + j; }
      }
    }
  }
  if (tid == 0) {
    float v = x[VV - 1];
    if (ordf(v) >= lo) {
      unsigned pos = atomicAdd(&s_cnt, 1u);
      if (pos < CAP) { cv[pos] = v; ci[pos] = VV - 1; }
    }
  }
  __syncthreads();
  const int ncand = (int)min(s_cnt, (unsigned)CAP);

  if (tid < 64) {
    // 50-round wave argmax (value desc, index asc)
    for (int it = 0; it < 50; ++it) {
      float bv = -INFINITY;
      int bi = 0x7FFFFFFF, bs = 0;
      for (int c = tid; c < ncand; c += 64) {
        float v = cv[c];
        int id = ci[c];
        if (v > bv || (v == bv && id < bi)) { bv = v; bi = id; bs = c; }
      }
      #pragma unroll
      for (int off = 32; off; off >>= 1) {
        float ov = __shfl_xor(bv, off);
        int oi = __shfl_xor(bi, off);
        int os = __shfl_xor(bs, off);
        if (ov > bv || (ov == bv && oi < bi)) { bv = ov; bi = oi; bs = os; }
      }
      if (tid == 0) {
        top_v[it] = bv;
        top_i[it] = bi;
        cv[bs] = -INFINITY;   // same-wave LDS ops in-order
      }
    }

    // lane-parallel softmax / top-p / gumbel over the 50 survivors
    float tv = (tid < 50) ? top_v[tid] : -3e38f;
    float mx = top_v[0];
    float sp = (tid < 50) ? expf(tv - mx) : 0.f;
    float Z = sp;
    #pragma unroll
    for (int off = 32; off; off >>= 1) Z += __shfl_xor(Z, off);
    float pref = sp;   // inclusive prefix over lane order
    #pragma unroll
    for (int off = 1; off < 64; off <<= 1) {
      float o = __shfl_up(pref, off);
      if (tid >= off) pref += o;
    }
    float excl = (pref - sp) / Z;
    bool keep = (tid < 50) && ((tid == 0) || (excl < 0.95f));
    float spk = keep ? sp : 0.f;
    float Z2 = spk;
    #pragma unroll
    for (int off = 32; off; off >>= 1) Z2 += __shfl_xor(Z2, off);

    float bt = -3e38f;
    int bidx = 0x7FFFFFFF;
    if (keep) {
      int idx = top_i[tid];
      probs[(size_t)row * VV + idx] = sp / Z2;
      bt = tv + gumbel_at((unsigned)((size_t)row * VV + idx));
      bidx = idx;
    }
    #pragma unroll
    for (int off = 32; off; off >>= 1) {
      float ot = __shfl_xor(bt, off);
      int oi = __shfl_xor(bidx, off);
      if (ot > bt || (ot == bt && oi < bidx)) { bt = ot; bidx = oi; }
    }
    if (tid == 0) tokens[row] = (float)bidx;
  }
}

// ---------------- launch --------------------------------------------------
extern "C" void kernel_launch(void* const* d_in, const int* in_sizes, int n_in,
                              void* d_out, int out_size, void* d_ws, size_t ws_size,
                              hipStream_t stream) {
  const float* psi_r = (const float*)d_in[0];
  const float* psi_i = (const float*)d_in[1];
  const float* Wr    = (const float*)d_in[2];
  const float* Wi    = (const float*)d_in[3];
  const float* bias  = (const float*)d_in[4];
  float* out = (float*)d_out;

  ushort* a_buf = (ushort*)d_ws;
  float* ws4    = (float*)((char*)d_ws + WS_ABUF_BYTES);

  float* logits = out;
  float* tokens = out + OUT_TOKENS;
  float* probs  = out + OUT_PROBS;
  float* logpr  = out + OUT_LOGPR;

  k_prep<<<256, 256, 0, stream>>>(psi_r, psi_i, a_buf);
  const int nblk = (VV + BN - 1) / BN;  // 786
  k_gemm<<<nblk, GT, 0, stream>>>((const uint4*)a_buf, Wr, Wi, bias, logits);
  k_stats<<<MM, 1024, 0, stream>>>(logits, ws4);
  k_logprobs<<<2048, 1024, 0, stream>>>(logits, ws4, logpr, probs);
  k_collect<<<MM, 1024, 0, stream>>>(logits, ws4, probs, tokens);
}

// Round 6
// 285.584 us; speedup vs baseline: 4.8940x; 1.0081x over previous
//
#include <hip/hip_runtime.h>
#include <stdint.h>
#include <math.h>

// Problem constants
#define MM 256          // B*S = 32*8
#define KD 1024         // D
#define K2 2048         // combined K (real|imag)
#define VV 50257        // vocab
#define NF4 (VV / 4)    // 12564 float4 slots; elem 50256 is the tail

static constexpr size_t OUT_TOKENS = (size_t)MM * VV;            // 12865792
static constexpr size_t OUT_PROBS  = OUT_TOKENS + MM;            // 12866048
static constexpr size_t OUT_LOGPR  = OUT_PROBS + (size_t)MM * VV;// 25731840

// ws layout: [0, 2MB) packed A ; [2MB, +4KB) row stats (4 f32/row)
#define WS_ABUF_BYTES (2u * 1024u * 1024u)

typedef __attribute__((ext_vector_type(8))) short bf16x8;
typedef __attribute__((ext_vector_type(4))) float f32x4;

// ---------------- bf16 split helpers --------------------------------------
__device__ __forceinline__ ushort f2bf(float x) {
  unsigned u = __float_as_uint(x);
  unsigned r = u + 0x7FFFu + ((u >> 16) & 1u);   // RNE
  return (ushort)(r >> 16);
}
__device__ __forceinline__ float bf2f(ushort h) {
  return __uint_as_float(((unsigned)h) << 16);
}

// ---------------- Threefry-2x32-20 (JAX-compatible) ----------------
__device__ __forceinline__ unsigned rotl32(unsigned x, int r) {
  return (x << r) | (x >> (32 - r));
}

__device__ __forceinline__ uint2 threefry2x32(unsigned k0, unsigned k1,
                                              unsigned x0, unsigned x1) {
  unsigned ks[3] = {k0, k1, k0 ^ k1 ^ 0x1BD11BDAu};
  const int rot[8] = {13, 15, 26, 6, 17, 29, 16, 24};
  x0 += ks[0]; x1 += ks[1];
  #pragma unroll
  for (int g = 0; g < 5; ++g) {
    const int base = (g & 1) ? 4 : 0;
    #pragma unroll
    for (int i = 0; i < 4; ++i) {
      x0 += x1;
      x1 = rotl32(x1, rot[base + i]);
      x1 ^= x0;
    }
    x0 += ks[(g + 1) % 3];
    x1 += ks[(g + 2) % 3] + (unsigned)(g + 1);
  }
  return make_uint2(x0, x1);
}

__device__ __forceinline__ float gumbel_at(unsigned flat) {
  uint2 r = threefry2x32(0u, 42u, 0u, flat);
  unsigned w = r.x ^ r.y;
  unsigned fb = (w >> 9) | 0x3F800000u;
  float f = __uint_as_float(fb) - 1.0f;
  const float tiny = 1.1754943508222875e-38f;
  float u = fmaxf(tiny, f + tiny);
  float t1 = (float)log((double)u);
  float t3 = (float)log((double)(-t1));
  return -t3;
}

// ---------------- K0: pack psi -> hi/lo bf16 in MFMA fragment layout ------
// chunk c = (s*16 + mb)*2 + h ; each chunk = 64 lanes x 8 shorts = 1KB.
__global__ __launch_bounds__(256)
void k_prep(const float* __restrict__ psi_r, const float* __restrict__ psi_i,
            ushort* __restrict__ a_buf) {
  int t = blockIdx.x * 256 + threadIdx.x;   // 65536 threads: (s, mb, lane)
  int lane = t & 63;
  int mb = (t >> 6) & 15;
  int s = t >> 10;                          // 0..63
  int lr = lane & 15, lg = lane >> 4;
  int m = mb * 16 + lr;
  int kloc = (s & 31) * 32 + lg * 8;
  const float* __restrict__ src = (s < 32) ? psi_r : psi_i;
  float4 v0 = *reinterpret_cast<const float4*>(&src[m * KD + kloc]);
  float4 v1 = *reinterpret_cast<const float4*>(&src[m * KD + kloc + 4]);
  float in[8] = {v0.x, v0.y, v0.z, v0.w, v1.x, v1.y, v1.z, v1.w};
  ushort h[8], l[8];
  #pragma unroll
  for (int j = 0; j < 8; ++j) {
    h[j] = f2bf(in[j]);
    l[j] = f2bf(in[j] - bf2f(h[j]));
  }
  size_t base = ((size_t)(s * 16 + mb) * 2) * 512 + (size_t)lane * 8;
  #pragma unroll
  for (int j = 0; j < 8; ++j) {
    a_buf[base + j] = h[j];
    a_buf[base + 512 + j] = l[j];
  }
}

// ---------------- K1: pipelined split-bf16 MFMA GEMM, 4 waves x 64m -------
#define BN 64
#define BK 64
#define GT 256

__global__ __launch_bounds__(GT, 2)
void k_gemm(const uint4* __restrict__ a_buf,
            const float* __restrict__ Wr, const float* __restrict__ Wi,
            const float* __restrict__ bias, float* __restrict__ logits) {
  __shared__ ushort sBh[2][BN * BK];   // 8 KB per buf
  __shared__ ushort sBl[2][BN * BK];

  const int tid  = threadIdx.x;
  const int lane = tid & 63;
  const int wid  = tid >> 6;    // 0..3 -> m block of 64
  const int vb   = blockIdx.x * BN;
  const int lr = lane & 15;
  const int lg = lane >> 4;

  // B staging coords: 4 threads per row, 16 f32 per thread
  const int brow = tid >> 2;          // 0..63
  const int bcol = (tid & 3) << 4;    // 0,16,32,48
  const int gn   = vb + brow;
  const int eo0  = brow * BK + (bcol ^ ((brow & 7) << 3));
  const int eo1  = brow * BK + ((bcol + 8) ^ ((brow & 7) << 3));

  f32x4 acc[4][4];
  #pragma unroll
  for (int i = 0; i < 4; ++i)
    #pragma unroll
    for (int j = 0; j < 4; ++j)
      #pragma unroll
      for (int q = 0; q < 4; ++q) acc[i][j][q] = 0.f;

  // prologue: W tile 0 into regs (4 float4)
  float4 w0 = make_float4(0.f, 0.f, 0.f, 0.f), w1 = w0, w2 = w0, w3 = w0;
  if (gn < VV) {
    const float* p = &Wr[(size_t)gn * KD + bcol];
    w0 = *reinterpret_cast<const float4*>(p);
    w1 = *reinterpret_cast<const float4*>(p + 4);
    w2 = *reinterpret_cast<const float4*>(p + 8);
    w3 = *reinterpret_cast<const float4*>(p + 12);
  }

  int cur = 0;
  for (int s2 = 0; s2 < K2 / BK; ++s2) {   // 32 steps
    // ---- issue A loads for THIS step (complete during stage+barrier)
    uint4 vah[2][4], val[2][4];   // [kq][mi]
    #pragma unroll
    for (int kq = 0; kq < 2; ++kq) {
      #pragma unroll
      for (int mi = 0; mi < 4; ++mi) {
        int chunk2 = (((s2 * 2 + kq) * 16) + wid * 4 + mi) * 2;
        vah[kq][mi] = a_buf[(size_t)chunk2 * 64 + lane];
        val[kq][mi] = a_buf[(size_t)(chunk2 + 1) * 64 + lane];
      }
    }
    // ---- convert W[s2] regs, write LDS buf[cur]
    {
      float in[16] = {w0.x, w0.y, w0.z, w0.w, w1.x, w1.y, w1.z, w1.w,
                      w2.x, w2.y, w2.z, w2.w, w3.x, w3.y, w3.z, w3.w};
      ushort h[16], l[16];
      #pragma unroll
      for (int j = 0; j < 16; ++j) {
        h[j] = f2bf(in[j]);
        l[j] = f2bf(in[j] - bf2f(h[j]));
      }
      *reinterpret_cast<uint4*>(&sBh[cur][eo0]) =
          make_uint4((unsigned)h[0] | ((unsigned)h[1] << 16),
                     (unsigned)h[2] | ((unsigned)h[3] << 16),
                     (unsigned)h[4] | ((unsigned)h[5] << 16),
                     (unsigned)h[6] | ((unsigned)h[7] << 16));
      *reinterpret_cast<uint4*>(&sBh[cur][eo1]) =
          make_uint4((unsigned)h[8] | ((unsigned)h[9] << 16),
                     (unsigned)h[10] | ((unsigned)h[11] << 16),
                     (unsigned)h[12] | ((unsigned)h[13] << 16),
                     (unsigned)h[14] | ((unsigned)h[15] << 16));
      *reinterpret_cast<uint4*>(&sBl[cur][eo0]) =
          make_uint4((unsigned)l[0] | ((unsigned)l[1] << 16),
                     (unsigned)l[2] | ((unsigned)l[3] << 16),
                     (unsigned)l[4] | ((unsigned)l[5] << 16),
                     (unsigned)l[6] | ((unsigned)l[7] << 16));
      *reinterpret_cast<uint4*>(&sBl[cur][eo1]) =
          make_uint4((unsigned)l[8] | ((unsigned)l[9] << 16),
                     (unsigned)l[10] | ((unsigned)l[11] << 16),
                     (unsigned)l[12] | ((unsigned)l[13] << 16),
                     (unsigned)l[14] | ((unsigned)l[15] << 16));
    }
    // ---- issue W[s2+1] load AFTER staging-use: stays in flight across barrier
    if (s2 < K2 / BK - 1) {
      int kk = (s2 + 1) * BK;
      const float* __restrict__ Bs = (kk < KD) ? Wr : Wi;
      int ko = kk & (KD - 1);
      if (gn < VV) {
        const float* p = &Bs[(size_t)gn * KD + ko + bcol];
        w0 = *reinterpret_cast<const float4*>(p);
        w1 = *reinterpret_cast<const float4*>(p + 4);
        w2 = *reinterpret_cast<const float4*>(p + 8);
        w3 = *reinterpret_cast<const float4*>(p + 12);
      }
    }
    // ---- raw barrier: LDS visibility only, NO vmcnt drain
    asm volatile("s_waitcnt lgkmcnt(0)" ::: "memory");
    asm volatile("s_barrier" ::: "memory");

    // ---- compute: B frags from LDS, A from regs
    #pragma unroll
    for (int kq = 0; kq < 2; ++kq) {
      bf16x8 bh[4], bl[4];
      #pragma unroll
      for (int ni = 0; ni < 4; ++ni) {
        int r = ni * 16 + lr;
        int eoff = r * BK + ((kq * 32 + lg * 8) ^ ((r & 7) << 3));
        bh[ni] = *reinterpret_cast<const bf16x8*>(&sBh[cur][eoff]);
        bl[ni] = *reinterpret_cast<const bf16x8*>(&sBl[cur][eoff]);
      }
      __builtin_amdgcn_s_setprio(1);
      #pragma unroll
      for (int mi = 0; mi < 4; ++mi) {
        bf16x8 ah = *reinterpret_cast<bf16x8*>(&vah[kq][mi]);
        bf16x8 al = *reinterpret_cast<bf16x8*>(&val[kq][mi]);
        #pragma unroll
        for (int ni = 0; ni < 4; ++ni) {
          acc[mi][ni] = __builtin_amdgcn_mfma_f32_16x16x32_bf16(ah, bh[ni], acc[mi][ni], 0, 0, 0);
          acc[mi][ni] = __builtin_amdgcn_mfma_f32_16x16x32_bf16(al, bh[ni], acc[mi][ni], 0, 0, 0);
          acc[mi][ni] = __builtin_amdgcn_mfma_f32_16x16x32_bf16(ah, bl[ni], acc[mi][ni], 0, 0, 0);
        }
      }
      __builtin_amdgcn_s_setprio(0);
    }
    cur ^= 1;
  }

  // epilogue: D layout col=lane&15, row=(lane>>4)*4+reg
  #pragma unroll
  for (int ni = 0; ni < 4; ++ni) {
    int n = vb + ni * 16 + lr;
    if (n < VV) {
      float b = bias[n];
      #pragma unroll
      for (int mi = 0; mi < 4; ++mi) {
        #pragma unroll
        for (int j = 0; j < 4; ++j) {
          int m = wid * 64 + mi * 16 + lg * 4 + j;
          logits[(size_t)m * VV + n] = acc[mi][ni][j] + b;
        }
      }
    }
  }
}

// ---------------- K2: fused row stats (max, lse) + top-50 threshold -------
__device__ __forceinline__ unsigned ordf(float f) {
  unsigned u = __float_as_uint(f);
  return u ^ ((u >> 31) ? 0xFFFFFFFFu : 0x80000000u);
}

#define HREP 4
#define HSTRIDE 4097

__global__ __launch_bounds__(1024)
void k_stats(const float* __restrict__ logits, float* __restrict__ ws4) {
  const int row = blockIdx.x;
  const int tid = threadIdx.x;
  const float* __restrict__ x = logits + (size_t)row * VV;

  __shared__ unsigned hist[HREP * HSTRIDE];   // 64 KB + eps
  __shared__ float pm[16], ps[16];

  for (int i = tid; i < HREP * HSTRIDE; i += 1024) hist[i] = 0u;
  __syncthreads();

  const int rep = (tid & 3) * HSTRIDE;
  float lm = -INFINITY, ls = 0.f;
  for (int i4 = tid; i4 < NF4; i4 += 1024) {
    float4 v4 = *reinterpret_cast<const float4*>(&x[i4 * 4]);
    float vs[4] = {v4.x, v4.y, v4.z, v4.w};
    #pragma unroll
    for (int j = 0; j < 4; ++j) {
      float v = vs[j];
      atomicAdd(&hist[rep + (ordf(v) >> 20)], 1u);
      if (v <= lm) {
        ls += expf(v - lm);
      } else {
        ls = ls * expf(lm - v) + 1.f;
        lm = v;
      }
    }
  }
  if (tid == 0) {   // tail element
    float v = x[VV - 1];
    atomicAdd(&hist[ordf(v) >> 20], 1u);
    if (v <= lm) ls += expf(v - lm);
    else { ls = ls * expf(lm - v) + 1.f; lm = v; }
  }
  // wave-level (m,s) reduce
  #pragma unroll
  for (int off = 32; off; off >>= 1) {
    float om = __shfl_xor(lm, off);
    float os = __shfl_xor(ls, off);
    float M = fmaxf(lm, om);
    ls = ls * expf(lm - M) + os * expf(om - M);
    lm = M;
  }
  if ((tid & 63) == 0) { pm[tid >> 6] = lm; ps[tid >> 6] = ls; }
  __syncthreads();

  // merge histogram replicas into replica 0
  for (int b = tid; b < 4096; b += 1024)
    hist[b] = hist[b] + hist[HSTRIDE + b] + hist[2 * HSTRIDE + b] + hist[3 * HSTRIDE + b];
  __syncthreads();

  if (tid < 64) {
    // merge 16 wave partials (lanes >=16 use finite identity to avoid NaN)
    float m2 = (tid < 16) ? pm[tid] : -3e38f;
    float s2 = (tid < 16) ? ps[tid] : 0.f;
    #pragma unroll
    for (int off = 8; off; off >>= 1) {
      float om = __shfl_xor(m2, off);
      float os = __shfl_xor(s2, off);
      float M = fmaxf(m2, om);
      s2 = s2 * expf(m2 - M) + os * expf(om - M);
      m2 = M;
    }
    // segment sums of hist: lane l owns bins [l*64, l*64+64) (rotated reads)
    unsigned seg = 0;
    #pragma unroll 8
    for (int b = 0; b < 64; ++b) seg += hist[tid * 64 + ((b + tid) & 63)];
    // suffix scan: suf[l] = sum_{j>=l} seg[j]
    unsigned suf = seg;
    #pragma unroll
    for (int off = 1; off < 64; off <<= 1) {
      unsigned o = __shfl_down(suf, off);
      if (tid + off < 64) suf += o;
    }
    unsigned long long mk = __ballot(suf >= 50u);
    int lstar = 63 - __builtin_clzll(mk);       // highest segment with suffix>=50
    unsigned above = (lstar < 63) ? (unsigned)__shfl((int)suf, lstar + 1) : 0u;
    if (tid == 0) {
      unsigned cum = above;
      int bin = lstar * 64;
      for (int b = 63; b >= 0; --b) {
        cum += hist[lstar * 64 + b];
        if (cum >= 50u) { bin = lstar * 64 + b; break; }
      }
      ws4[row * 4 + 0] = m2;
      ws4[row * 4 + 1] = logf(s2);
      ws4[row * 4 + 2] = __uint_as_float((unsigned)bin << 20);
    }
  }
}

// ---------------- K3: fused log_probs + probs-zero + collect + sample -----
#define CAP 1024

__global__ __launch_bounds__(1024)
void k_post(const float* __restrict__ logits, const float* __restrict__ ws4,
            float* __restrict__ logpr, float* __restrict__ probs,
            float* __restrict__ tokens) {
  const int row = blockIdx.x;
  const int tid = threadIdx.x;
  const float* __restrict__ x = logits + (size_t)row * VV;
  float* __restrict__ lp = logpr + (size_t)row * VV;
  float* __restrict__ pr = probs + (size_t)row * VV;

  __shared__ float cv[CAP];
  __shared__ int   ci[CAP];
  __shared__ unsigned s_cnt;
  __shared__ float top_v[50];
  __shared__ int   top_i[50];

  if (tid == 0) s_cnt = 0u;
  __syncthreads();

  const float mx = ws4[row * 4 + 0];
  const float lz = ws4[row * 4 + 1];
  const unsigned lo = __float_as_uint(ws4[row * 4 + 2]);
  const float4 z4 = make_float4(0.f, 0.f, 0.f, 0.f);

  for (int i4 = tid; i4 < NF4; i4 += 1024) {
    float4 v = *reinterpret_cast<const float4*>(&x[i4 * 4]);
    *reinterpret_cast<float4*>(&lp[i4 * 4]) =
        make_float4((v.x - mx) - lz, (v.y - mx) - lz,
                    (v.z - mx) - lz, (v.w - mx) - lz);
    *reinterpret_cast<float4*>(&pr[i4 * 4]) = z4;
    float vs[4] = {v.x, v.y, v.z, v.w};
    #pragma unroll
    for (int j = 0; j < 4; ++j) {
      if (ordf(vs[j]) >= lo) {
        unsigned pos = atomicAdd(&s_cnt, 1u);
        if (pos < CAP) { cv[pos] = vs[j]; ci[pos] = i4 * 4 + j; }
      }
    }
  }
  if (tid == 0) {
    float v = x[VV - 1];
    lp[VV - 1] = (v - mx) - lz;
    pr[VV - 1] = 0.f;
    if (ordf(v) >= lo) {
      unsigned pos = atomicAdd(&s_cnt, 1u);
      if (pos < CAP) { cv[pos] = v; ci[pos] = VV - 1; }
    }
  }
  __syncthreads();
  const int ncand = (int)min(s_cnt, (unsigned)CAP);

  if (tid < 64) {
    // 50-round wave argmax (value desc, index asc)
    for (int it = 0; it < 50; ++it) {
      float bv = -INFINITY;
      int bi = 0x7FFFFFFF, bs = 0;
      for (int c = tid; c < ncand; c += 64) {
        float v = cv[c];
        int id = ci[c];
        if (v > bv || (v == bv && id < bi)) { bv = v; bi = id; bs = c; }
      }
      #pragma unroll
      for (int off = 32; off; off >>= 1) {
        float ov = __shfl_xor(bv, off);
        int oi = __shfl_xor(bi, off);
        int os = __shfl_xor(bs, off);
        if (ov > bv || (ov == bv && oi < bi)) { bv = ov; bi = oi; bs = os; }
      }
      if (tid == 0) {
        top_v[it] = bv;
        top_i[it] = bi;
        cv[bs] = -INFINITY;   // same-wave LDS ops in-order
      }
    }

    // lane-parallel softmax / top-p / gumbel over the 50 survivors
    float tv = (tid < 50) ? top_v[tid] : -3e38f;
    float m0 = top_v[0];
    float sp = (tid < 50) ? expf(tv - m0) : 0.f;
    float Z = sp;
    #pragma unroll
    for (int off = 32; off; off >>= 1) Z += __shfl_xor(Z, off);
    float pref = sp;   // inclusive prefix over lane order
    #pragma unroll
    for (int off = 1; off < 64; off <<= 1) {
      float o = __shfl_up(pref, off);
      if (tid >= off) pref += o;
    }
    float excl = (pref - sp) / Z;
    bool keep = (tid < 50) && ((tid == 0) || (excl < 0.95f));
    float spk = keep ? sp : 0.f;
    float Z2 = spk;
    #pragma unroll
    for (int off = 32; off; off >>= 1) Z2 += __shfl_xor(Z2, off);

    float bt = -3e38f;
    int bidx = 0x7FFFFFFF;
    if (keep) {
      int idx = top_i[tid];
      pr[idx] = sp / Z2;
      bt = tv + gumbel_at((unsigned)((size_t)row * VV + idx));
      bidx = idx;
    }
    #pragma unroll
    for (int off = 32; off; off >>= 1) {
      float ot = __shfl_xor(bt, off);
      int oi = __shfl_xor(bidx, off);
      if (ot > bt || (ot == bt && oi < bidx)) { bt = ot; bidx = oi; }
    }
    if (tid == 0) tokens[row] = (float)bidx;
  }
}

// ---------------- launch --------------------------------------------------
extern "C" void kernel_launch(void* const* d_in, const int* in_sizes, int n_in,
                              void* d_out, int out_size, void* d_ws, size_t ws_size,
                              hipStream_t stream) {
  const float* psi_r = (const float*)d_in[0];
  const float* psi_i = (const float*)d_in[1];
  const float* Wr    = (const float*)d_in[2];
  const float* Wi    = (const float*)d_in[3];
  const float* bias  = (const float*)d_in[4];
  float* out = (float*)d_out;

  ushort* a_buf = (ushort*)d_ws;
  float* ws4    = (float*)((char*)d_ws + WS_ABUF_BYTES);

  float* logits = out;
  float* tokens = out + OUT_TOKENS;
  float* probs  = out + OUT_PROBS;
  float* logpr  = out + OUT_LOGPR;

  k_prep<<<256, 256, 0, stream>>>(psi_r, psi_i, a_buf);
  const int nblk = (VV + BN - 1) / BN;  // 786
  k_gemm<<<nblk, GT, 0, stream>>>((const uint4*)a_buf, Wr, Wi, bias, logits);
  k_stats<<<MM, 1024, 0, stream>>>(logits, ws4);
  k_post<<<MM, 1024, 0, stream>>>(logits, ws4, logpr, probs, tokens);
}

// Round 7
// 284.084 us; speedup vs baseline: 4.9199x; 1.0053x over previous
//
#include <hip/hip_runtime.h>
#include <stdint.h>
#include <math.h>

// Problem constants
#define MM 256          // B*S = 32*8
#define KD 1024         // D
#define K2 2048         // combined K (real|imag)
#define VV 50257        // vocab
#define NF4 (VV / 4)    // 12564 float4 slots; elem 50256 is the tail
#define NSTEP 32        // K2 / BK

static constexpr size_t OUT_TOKENS = (size_t)MM * VV;            // 12865792
static constexpr size_t OUT_PROBS  = OUT_TOKENS + MM;            // 12866048
static constexpr size_t OUT_LOGPR  = OUT_PROBS + (size_t)MM * VV;// 25731840

// ws layout: [0, 2MB) packed A ; [2MB, +4KB) row stats (4 f32/row)
#define WS_ABUF_BYTES (2u * 1024u * 1024u)

typedef __attribute__((ext_vector_type(8))) short bf16x8;
typedef __attribute__((ext_vector_type(4))) float f32x4;

// ---------------- bf16 split helpers --------------------------------------
__device__ __forceinline__ ushort f2bf(float x) {
  unsigned u = __float_as_uint(x);
  unsigned r = u + 0x7FFFu + ((u >> 16) & 1u);   // RNE
  return (ushort)(r >> 16);
}
__device__ __forceinline__ float bf2f(ushort h) {
  return __uint_as_float(((unsigned)h) << 16);
}

// ---------------- Threefry-2x32-20 (JAX-compatible) ----------------
__device__ __forceinline__ unsigned rotl32(unsigned x, int r) {
  return (x << r) | (x >> (32 - r));
}

__device__ __forceinline__ uint2 threefry2x32(unsigned k0, unsigned k1,
                                              unsigned x0, unsigned x1) {
  unsigned ks[3] = {k0, k1, k0 ^ k1 ^ 0x1BD11BDAu};
  const int rot[8] = {13, 15, 26, 6, 17, 29, 16, 24};
  x0 += ks[0]; x1 += ks[1];
  #pragma unroll
  for (int g = 0; g < 5; ++g) {
    const int base = (g & 1) ? 4 : 0;
    #pragma unroll
    for (int i = 0; i < 4; ++i) {
      x0 += x1;
      x1 = rotl32(x1, rot[base + i]);
      x1 ^= x0;
    }
    x0 += ks[(g + 1) % 3];
    x1 += ks[(g + 2) % 3] + (unsigned)(g + 1);
  }
  return make_uint2(x0, x1);
}

__device__ __forceinline__ float gumbel_at(unsigned flat) {
  uint2 r = threefry2x32(0u, 42u, 0u, flat);
  unsigned w = r.x ^ r.y;
  unsigned fb = (w >> 9) | 0x3F800000u;
  float f = __uint_as_float(fb) - 1.0f;
  const float tiny = 1.1754943508222875e-38f;
  float u = fmaxf(tiny, f + tiny);
  float t1 = (float)log((double)u);
  float t3 = (float)log((double)(-t1));
  return -t3;
}

// ---------------- K0: pack psi -> hi/lo bf16 in MFMA fragment layout ------
__global__ __launch_bounds__(256)
void k_prep(const float* __restrict__ psi_r, const float* __restrict__ psi_i,
            ushort* __restrict__ a_buf) {
  int t = blockIdx.x * 256 + threadIdx.x;   // 65536 threads: (s, mb, lane)
  int lane = t & 63;
  int mb = (t >> 6) & 15;
  int s = t >> 10;                          // 0..63
  int lr = lane & 15, lg = lane >> 4;
  int m = mb * 16 + lr;
  int kloc = (s & 31) * 32 + lg * 8;
  const float* __restrict__ src = (s < 32) ? psi_r : psi_i;
  float4 v0 = *reinterpret_cast<const float4*>(&src[m * KD + kloc]);
  float4 v1 = *reinterpret_cast<const float4*>(&src[m * KD + kloc + 4]);
  float in[8] = {v0.x, v0.y, v0.z, v0.w, v1.x, v1.y, v1.z, v1.w};
  ushort h[8], l[8];
  #pragma unroll
  for (int j = 0; j < 8; ++j) {
    h[j] = f2bf(in[j]);
    l[j] = f2bf(in[j] - bf2f(h[j]));
  }
  size_t base = ((size_t)(s * 16 + mb) * 2) * 512 + (size_t)lane * 8;
  #pragma unroll
  for (int j = 0; j < 8; ++j) {
    a_buf[base + j] = h[j];
    a_buf[base + 512 + j] = l[j];
  }
}

// ---------------- K1: deep-pipelined split-bf16 MFMA GEMM -----------------
#define BN 64
#define BK 64
#define GT 256

struct W4 { float4 a, b, c, d; };
struct A8 { uint4 h[4]; uint4 l[4]; };

__device__ __forceinline__ void loadW(W4& w, const float* __restrict__ Wr,
                                      const float* __restrict__ Wi,
                                      int t, int gn, int bcol) {
  const float* __restrict__ Bs = (t < 16) ? Wr : Wi;
  int ko = (t << 6) & (KD - 1);
  if (gn < VV) {
    const float* p = &Bs[(size_t)gn * KD + ko + bcol];
    w.a = *reinterpret_cast<const float4*>(p);
    w.b = *reinterpret_cast<const float4*>(p + 4);
    w.c = *reinterpret_cast<const float4*>(p + 8);
    w.d = *reinterpret_cast<const float4*>(p + 12);
  }
}

__device__ __forceinline__ void stageW(const W4& w, ushort* __restrict__ bh,
                                       ushort* __restrict__ bl, int eo0, int eo1) {
  float in[16] = {w.a.x, w.a.y, w.a.z, w.a.w, w.b.x, w.b.y, w.b.z, w.b.w,
                  w.c.x, w.c.y, w.c.z, w.c.w, w.d.x, w.d.y, w.d.z, w.d.w};
  ushort h[16], l[16];
  #pragma unroll
  for (int j = 0; j < 16; ++j) {
    h[j] = f2bf(in[j]);
    l[j] = f2bf(in[j] - bf2f(h[j]));
  }
  *reinterpret_cast<uint4*>(&bh[eo0]) =
      make_uint4((unsigned)h[0] | ((unsigned)h[1] << 16),
                 (unsigned)h[2] | ((unsigned)h[3] << 16),
                 (unsigned)h[4] | ((unsigned)h[5] << 16),
                 (unsigned)h[6] | ((unsigned)h[7] << 16));
  *reinterpret_cast<uint4*>(&bh[eo1]) =
      make_uint4((unsigned)h[8] | ((unsigned)h[9] << 16),
                 (unsigned)h[10] | ((unsigned)h[11] << 16),
                 (unsigned)h[12] | ((unsigned)h[13] << 16),
                 (unsigned)h[14] | ((unsigned)h[15] << 16));
  *reinterpret_cast<uint4*>(&bl[eo0]) =
      make_uint4((unsigned)l[0] | ((unsigned)l[1] << 16),
                 (unsigned)l[2] | ((unsigned)l[3] << 16),
                 (unsigned)l[4] | ((unsigned)l[5] << 16),
                 (unsigned)l[6] | ((unsigned)l[7] << 16));
  *reinterpret_cast<uint4*>(&bl[eo1]) =
      make_uint4((unsigned)l[8] | ((unsigned)l[9] << 16),
                 (unsigned)l[10] | ((unsigned)l[11] << 16),
                 (unsigned)l[12] | ((unsigned)l[13] << 16),
                 (unsigned)l[14] | ((unsigned)l[15] << 16));
}

__device__ __forceinline__ void loadA(A8& A, const uint4* __restrict__ a_buf,
                                      int s, int kq, int wid, int lane) {
  #pragma unroll
  for (int mi = 0; mi < 4; ++mi) {
    int chunk2 = (((s * 2 + kq) * 16) + wid * 4 + mi) * 2;
    A.h[mi] = a_buf[(size_t)chunk2 * 64 + lane];
    A.l[mi] = a_buf[(size_t)(chunk2 + 1) * 64 + lane];
  }
}

__device__ __forceinline__ void computeKQ(f32x4 (&acc)[4][4], const A8& A,
                                          const ushort* __restrict__ bhp,
                                          const ushort* __restrict__ blp,
                                          int kq, int lr, int lg) {
  bf16x8 bh[4], bl[4];
  #pragma unroll
  for (int ni = 0; ni < 4; ++ni) {
    int r = ni * 16 + lr;
    int eoff = r * BK + ((kq * 32 + lg * 8) ^ ((r & 7) << 3));
    bh[ni] = *reinterpret_cast<const bf16x8*>(&bhp[eoff]);
    bl[ni] = *reinterpret_cast<const bf16x8*>(&blp[eoff]);
  }
  __builtin_amdgcn_s_setprio(1);
  #pragma unroll
  for (int mi = 0; mi < 4; ++mi) {
    bf16x8 ah = *reinterpret_cast<const bf16x8*>(&A.h[mi]);
    bf16x8 al = *reinterpret_cast<const bf16x8*>(&A.l[mi]);
    #pragma unroll
    for (int ni = 0; ni < 4; ++ni) {
      acc[mi][ni] = __builtin_amdgcn_mfma_f32_16x16x32_bf16(ah, bh[ni], acc[mi][ni], 0, 0, 0);
      acc[mi][ni] = __builtin_amdgcn_mfma_f32_16x16x32_bf16(al, bh[ni], acc[mi][ni], 0, 0, 0);
      acc[mi][ni] = __builtin_amdgcn_mfma_f32_16x16x32_bf16(ah, bl[ni], acc[mi][ni], 0, 0, 0);
    }
  }
  __builtin_amdgcn_s_setprio(0);
}

__global__ __launch_bounds__(GT, 2)
void k_gemm(const uint4* __restrict__ a_buf,
            const float* __restrict__ Wr, const float* __restrict__ Wi,
            const float* __restrict__ bias, float* __restrict__ logits) {
  __shared__ ushort sBh[2][BN * BK];   // 8 KB per buf
  __shared__ ushort sBl[2][BN * BK];

  const int tid  = threadIdx.x;
  const int lane = tid & 63;
  const int wid  = tid >> 6;    // 0..3 -> m block of 64
  const int vb   = blockIdx.x * BN;
  const int lr = lane & 15;
  const int lg = lane >> 4;

  // B staging coords: 4 threads per row, 16 f32 per thread
  const int brow = tid >> 2;          // 0..63
  const int bcol = (tid & 3) << 4;    // 0,16,32,48
  const int gn   = vb + brow;
  const int eo0  = brow * BK + (bcol ^ ((brow & 7) << 3));
  const int eo1  = brow * BK + ((bcol + 8) ^ ((brow & 7) << 3));

  f32x4 acc[4][4];
  #pragma unroll
  for (int i = 0; i < 4; ++i)
    #pragma unroll
    for (int j = 0; j < 4; ++j)
      #pragma unroll
      for (int q = 0; q < 4; ++q) acc[i][j][q] = 0.f;

  // ---- prologue: W[0] -> wX -> buf0 ; W[1] -> wY ; W[2] -> wX ; A(0,0)
  W4 wX, wY;
  wX.a = wX.b = wX.c = wX.d = make_float4(0.f, 0.f, 0.f, 0.f);
  wY = wX;
  A8 A0, A1;
  loadW(wX, Wr, Wi, 0, gn, bcol);
  loadW(wY, Wr, Wi, 1, gn, bcol);
  loadA(A0, a_buf, 0, 0, wid, lane);
  stageW(wX, &sBh[0][0], &sBl[0][0], eo0, eo1);     // waits wX
  loadW(wX, Wr, Wi, 2, gn, bcol);
  asm volatile("s_waitcnt lgkmcnt(0)" ::: "memory");
  asm volatile("s_barrier" ::: "memory");

  // Steady state, unrolled by 2 for static W-set alternation.
  // Invariant at top of even step s: buf[s&1] = W[s]; wY = W[s+1]; wX = W[s+2] (in flight); A0 = A(s,0).
  for (int sp = 0; sp < NSTEP / 2; ++sp) {
    const int s0 = sp * 2;
    const int s1 = s0 + 1;
    // ---- step s0: read buf[0], stage W[s0+1] from wY -> buf[1]
    loadA(A1, a_buf, s0, 1, wid, lane);
    stageW(wY, &sBh[1][0], &sBl[1][0], eo0, eo1);
    if (s0 + 3 < NSTEP) loadW(wY, Wr, Wi, s0 + 3, gn, bcol);
    computeKQ(acc, A0, &sBh[0][0], &sBl[0][0], 0, lr, lg);
    loadA(A0, a_buf, s1, 0, wid, lane);
    computeKQ(acc, A1, &sBh[0][0], &sBl[0][0], 1, lr, lg);
    asm volatile("s_waitcnt lgkmcnt(0)" ::: "memory");
    asm volatile("s_barrier" ::: "memory");
    // ---- step s1: read buf[1], stage W[s1+1] from wX -> buf[0]
    loadA(A1, a_buf, s1, 1, wid, lane);
    if (s1 + 1 < NSTEP) stageW(wX, &sBh[0][0], &sBl[0][0], eo0, eo1);
    if (s1 + 3 < NSTEP) loadW(wX, Wr, Wi, s1 + 3, gn, bcol);
    computeKQ(acc, A0, &sBh[1][0], &sBl[1][0], 0, lr, lg);
    if (s1 < NSTEP - 1) loadA(A0, a_buf, s1 + 1, 0, wid, lane);
    computeKQ(acc, A1, &sBh[1][0], &sBl[1][0], 1, lr, lg);
    asm volatile("s_waitcnt lgkmcnt(0)" ::: "memory");
    asm volatile("s_barrier" ::: "memory");
  }

  // epilogue: D layout col=lane&15, row=(lane>>4)*4+reg
  #pragma unroll
  for (int ni = 0; ni < 4; ++ni) {
    int n = vb + ni * 16 + lr;
    if (n < VV) {
      float b = bias[n];
      #pragma unroll
      for (int mi = 0; mi < 4; ++mi) {
        #pragma unroll
        for (int j = 0; j < 4; ++j) {
          int m = wid * 64 + mi * 16 + lg * 4 + j;
          logits[(size_t)m * VV + n] = acc[mi][ni][j] + b;
        }
      }
    }
  }
}

// ---------------- K2: fused row stats (max, lse) + top-50 threshold -------
__device__ __forceinline__ unsigned ordf(float f) {
  unsigned u = __float_as_uint(f);
  return u ^ ((u >> 31) ? 0xFFFFFFFFu : 0x80000000u);
}

#define HREP 4
#define HSTRIDE 4097

__global__ __launch_bounds__(1024)
void k_stats(const float* __restrict__ logits, float* __restrict__ ws4) {
  const int row = blockIdx.x;
  const int tid = threadIdx.x;
  const float* __restrict__ x = logits + (size_t)row * VV;

  __shared__ unsigned hist[HREP * HSTRIDE];   // 64 KB + eps
  __shared__ float pm[16], ps[16];

  for (int i = tid; i < HREP * HSTRIDE; i += 1024) hist[i] = 0u;
  __syncthreads();

  const int rep = (tid & 3) * HSTRIDE;
  float lm = -INFINITY, ls = 0.f;
  for (int i4 = tid; i4 < NF4; i4 += 1024) {
    float4 v4 = *reinterpret_cast<const float4*>(&x[i4 * 4]);
    float vs[4] = {v4.x, v4.y, v4.z, v4.w};
    #pragma unroll
    for (int j = 0; j < 4; ++j) {
      float v = vs[j];
      atomicAdd(&hist[rep + (ordf(v) >> 20)], 1u);
      if (v <= lm) {
        ls += expf(v - lm);
      } else {
        ls = ls * expf(lm - v) + 1.f;
        lm = v;
      }
    }
  }
  if (tid == 0) {   // tail element
    float v = x[VV - 1];
    atomicAdd(&hist[ordf(v) >> 20], 1u);
    if (v <= lm) ls += expf(v - lm);
    else { ls = ls * expf(lm - v) + 1.f; lm = v; }
  }
  // wave-level (m,s) reduce
  #pragma unroll
  for (int off = 32; off; off >>= 1) {
    float om = __shfl_xor(lm, off);
    float os = __shfl_xor(ls, off);
    float M = fmaxf(lm, om);
    ls = ls * expf(lm - M) + os * expf(om - M);
    lm = M;
  }
  if ((tid & 63) == 0) { pm[tid >> 6] = lm; ps[tid >> 6] = ls; }
  __syncthreads();

  // merge histogram replicas into replica 0
  for (int b = tid; b < 4096; b += 1024)
    hist[b] = hist[b] + hist[HSTRIDE + b] + hist[2 * HSTRIDE + b] + hist[3 * HSTRIDE + b];
  __syncthreads();

  if (tid < 64) {
    // merge 16 wave partials (lanes >=16 use finite identity to avoid NaN)
    float m2 = (tid < 16) ? pm[tid] : -3e38f;
    float s2 = (tid < 16) ? ps[tid] : 0.f;
    #pragma unroll
    for (int off = 8; off; off >>= 1) {
      float om = __shfl_xor(m2, off);
      float os = __shfl_xor(s2, off);
      float M = fmaxf(m2, om);
      s2 = s2 * expf(m2 - M) + os * expf(om - M);
      m2 = M;
    }
    // segment sums of hist: lane l owns bins [l*64, l*64+64) (rotated reads)
    unsigned seg = 0;
    #pragma unroll 8
    for (int b = 0; b < 64; ++b) seg += hist[tid * 64 + ((b + tid) & 63)];
    // suffix scan: suf[l] = sum_{j>=l} seg[j]
    unsigned suf = seg;
    #pragma unroll
    for (int off = 1; off < 64; off <<= 1) {
      unsigned o = __shfl_down(suf, off);
      if (tid + off < 64) suf += o;
    }
    unsigned long long mk = __ballot(suf >= 50u);
    int lstar = 63 - __builtin_clzll(mk);       // highest segment with suffix>=50
    unsigned above = (lstar < 63) ? (unsigned)__shfl((int)suf, lstar + 1) : 0u;
    if (tid == 0) {
      unsigned cum = above;
      int bin = lstar * 64;
      for (int b = 63; b >= 0; --b) {
        cum += hist[lstar * 64 + b];
        if (cum >= 50u) { bin = lstar * 64 + b; break; }
      }
      ws4[row * 4 + 0] = m2;
      ws4[row * 4 + 1] = logf(s2);
      ws4[row * 4 + 2] = __uint_as_float((unsigned)bin << 20);
    }
  }
}

// ---------------- K3: fused log_probs + probs-zero + collect + sample -----
#define CAP 1024

__global__ __launch_bounds__(1024)
void k_post(const float* __restrict__ logits, const float* __restrict__ ws4,
            float* __restrict__ logpr, float* __restrict__ probs,
            float* __restrict__ tokens) {
  const int row = blockIdx.x;
  const int tid = threadIdx.x;
  const float* __restrict__ x = logits + (size_t)row * VV;
  float* __restrict__ lp = logpr + (size_t)row * VV;
  float* __restrict__ pr = probs + (size_t)row * VV;

  __shared__ float cv[CAP];
  __shared__ int   ci[CAP];
  __shared__ unsigned s_cnt;
  __shared__ float top_v[50];
  __shared__ int   top_i[50];

  if (tid == 0) s_cnt = 0u;
  __syncthreads();

  const float mx = ws4[row * 4 + 0];
  const float lz = ws4[row * 4 + 1];
  const unsigned lo = __float_as_uint(ws4[row * 4 + 2]);
  const float4 z4 = make_float4(0.f, 0.f, 0.f, 0.f);

  for (int i4 = tid; i4 < NF4; i4 += 1024) {
    float4 v = *reinterpret_cast<const float4*>(&x[i4 * 4]);
    *reinterpret_cast<float4*>(&lp[i4 * 4]) =
        make_float4((v.x - mx) - lz, (v.y - mx) - lz,
                    (v.z - mx) - lz, (v.w - mx) - lz);
    *reinterpret_cast<float4*>(&pr[i4 * 4]) = z4;
    float vs[4] = {v.x, v.y, v.z, v.w};
    #pragma unroll
    for (int j = 0; j < 4; ++j) {
      if (ordf(vs[j]) >= lo) {
        unsigned pos = atomicAdd(&s_cnt, 1u);
        if (pos < CAP) { cv[pos] = vs[j]; ci[pos] = i4 * 4 + j; }
      }
    }
  }
  if (tid == 0) {
    float v = x[VV - 1];
    lp[VV - 1] = (v - mx) - lz;
    pr[VV - 1] = 0.f;
    if (ordf(v) >= lo) {
      unsigned pos = atomicAdd(&s_cnt, 1u);
      if (pos < CAP) { cv[pos] = v; ci[pos] = VV - 1; }
    }
  }
  __syncthreads();
  const int ncand = (int)min(s_cnt, (unsigned)CAP);

  if (tid < 64) {
    // 50-round wave argmax (value desc, index asc)
    for (int it = 0; it < 50; ++it) {
      float bv = -INFINITY;
      int bi = 0x7FFFFFFF, bs = 0;
      for (int c = tid; c < ncand; c += 64) {
        float v = cv[c];
        int id = ci[c];
        if (v > bv || (v == bv && id < bi)) { bv = v; bi = id; bs = c; }
      }
      #pragma unroll
      for (int off = 32; off; off >>= 1) {
        float ov = __shfl_xor(bv, off);
        int oi = __shfl_xor(bi, off);
        int os = __shfl_xor(bs, off);
        if (ov > bv || (ov == bv && oi < bi)) { bv = ov; bi = oi; bs = os; }
      }
      if (tid == 0) {
        top_v[it] = bv;
        top_i[it] = bi;
        cv[bs] = -INFINITY;   // same-wave LDS ops in-order
      }
    }

    // lane-parallel softmax / top-p / gumbel over the 50 survivors
    float tv = (tid < 50) ? top_v[tid] : -3e38f;
    float m0 = top_v[0];
    float sp = (tid < 50) ? expf(tv - m0) : 0.f;
    float Z = sp;
    #pragma unroll
    for (int off = 32; off; off >>= 1) Z += __shfl_xor(Z, off);
    float pref = sp;   // inclusive prefix over lane order
    #pragma unroll
    for (int off = 1; off < 64; off <<= 1) {
      float o = __shfl_up(pref, off);
      if (tid >= off) pref += o;
    }
    float excl = (pref - sp) / Z;
    bool keep = (tid < 50) && ((tid == 0) || (excl < 0.95f));
    float spk = keep ? sp : 0.f;
    float Z2 = spk;
    #pragma unroll
    for (int off = 32; off; off >>= 1) Z2 += __shfl_xor(Z2, off);

    float bt = -3e38f;
    int bidx = 0x7FFFFFFF;
    if (keep) {
      int idx = top_i[tid];
      pr[idx] = sp / Z2;
      bt = tv + gumbel_at((unsigned)((size_t)row * VV + idx));
      bidx = idx;
    }
    #pragma unroll
    for (int off = 32; off; off >>= 1) {
      float ot = __shfl_xor(bt, off);
      int oi = __shfl_xor(bidx, off);
      if (ot > bt || (ot == bt && oi < bidx)) { bt = ot; bidx = oi; }
    }
    if (tid == 0) tokens[row] = (float)bidx;
  }
}

// ---------------- launch --------------------------------------------------
extern "C" void kernel_launch(void* const* d_in, const int* in_sizes, int n_in,
                              void* d_out, int out_size, void* d_ws, size_t ws_size,
                              hipStream_t stream) {
  const float* psi_r = (const float*)d_in[0];
  const float* psi_i = (const float*)d_in[1];
  const float* Wr    = (const float*)d_in[2];
  const float* Wi    = (const float*)d_in[3];
  const float* bias  = (const float*)d_in[4];
  float* out = (float*)d_out;

  ushort* a_buf = (ushort*)d_ws;
  float* ws4    = (float*)((char*)d_ws + WS_ABUF_BYTES);

  float* logits = out;
  float* tokens = out + OUT_TOKENS;
  float* probs  = out + OUT_PROBS;
  float* logpr  = out + OUT_LOGPR;

  k_prep<<<256, 256, 0, stream>>>(psi_r, psi_i, a_buf);
  const int nblk = (VV + BN - 1) / BN;  // 786
  k_gemm<<<nblk, GT, 0, stream>>>((const uint4*)a_buf, Wr, Wi, bias, logits);
  k_stats<<<MM, 1024, 0, stream>>>(logits, ws4);
  k_post<<<MM, 1024, 0, stream>>>(logits, ws4, logpr, probs, tokens);
}